// Round 7
// baseline (201.787 us; speedup 1.0000x reference)
//
#include <hip/hip_runtime.h>
#include <math.h>

// Problem constants (fixed by setup_inputs)
#define BB 4
#define SS 512
#define EE 512
#define NH 8
#define HD 64
#define NC 128
#define NTAB 4096  // table intervals over sa in [-0.4, 0.4]

typedef _Float16 f16x8 __attribute__((ext_vector_type(8)));
typedef float f32x4 __attribute__((ext_vector_type(4)));

struct HL { _Float16 h, l; };

__device__ __forceinline__ float clampf(float v, float lo, float hi) {
  return fminf(fmaxf(v, lo), hi);
}
__device__ __forceinline__ HL split16(float x) {
  HL r;
  r.h = (_Float16)x;
  r.l = (_Float16)(x - (float)r.h);
  return r;
}

__device__ __forceinline__ float waveRedSum(float v) {
#pragma unroll
  for (int o = 32; o; o >>= 1) v += __shfl_xor(v, o);
  return v;
}
__device__ __forceinline__ float waveRedMax(float v) {
#pragma unroll
  for (int o = 32; o; o >>= 1) v = fmaxf(v, __shfl_xor(v, o));
  return v;
}
// blockDim.x == 256 (4 waves) assumed
__device__ __forceinline__ float blockRedSum(float v, float* red) {
  int tid = threadIdx.x;
  v = waveRedSum(v);
  __syncthreads();
  if ((tid & 63) == 0) red[tid >> 6] = v;
  __syncthreads();
  return red[0] + red[1] + red[2] + red[3];
}
__device__ __forceinline__ float blockRedMax(float v, float* red) {
  int tid = threadIdx.x;
  v = waveRedMax(v);
  __syncthreads();
  if ((tid & 63) == 0) red[tid >> 6] = v;
  __syncthreads();
  return fmaxf(fmaxf(red[0], red[1]), fmaxf(red[2], red[3]));
}

// ---------------------------------------------------------------------------
// K_prep: fused preprocessing (all independent):
//   blocks [0,17): sigmoid table
//   blocks [17,529): split x -> f16 hi/lo
//   blocks [529,785): transpose+split the 4 weight matrices
__global__ __launch_bounds__(256) void k_prep(
    const float* __restrict__ w1, const float* __restrict__ b1,
    const float* __restrict__ w2, const float* __restrict__ b2,
    float* __restrict__ T, const float* __restrict__ x,
    _Float16* __restrict__ xh, _Float16* __restrict__ xl,
    const float* __restrict__ Wq, const float* __restrict__ Wk,
    const float* __restrict__ Wv, const float* __restrict__ Wo,
    _Float16* __restrict__ Wth, _Float16* __restrict__ Wtl) {
  const int bid = blockIdx.x;
  const int tid = threadIdx.x;
  if (bid < 17) {
    int idx = bid * 256 + tid;
    if (idx > NTAB) return;
    float sa = -0.4f + (float)idx * (0.8f / (float)NTAB);
    float ap = 0.f;
#pragma unroll 4
    for (int c = 0; c < NC; ++c) {
      float h = fminf(fmaxf(sa * w1[c] + b1[c], 0.f), 5.f);
      ap += h * w2[c];
    }
    ap = clampf(ap + b2[0], -5.f, 5.f);
    float tay = clampf(1.0f + 0.05f * (ap * 50.0f), 0.5f, 1.5f);
    T[idx] = 1.0f / (1.0f + expf(-tay));
  } else if (bid < 529) {
    int idx = ((bid - 17) * 256 + tid) * 8;
    float4 u0 = *(const float4*)(x + idx);
    float4 u1 = *(const float4*)(x + idx + 4);
    float f[8] = {u0.x, u0.y, u0.z, u0.w, u1.x, u1.y, u1.z, u1.w};
    f16x8 h, l;
#pragma unroll
    for (int j = 0; j < 8; ++j) {
      HL r = split16(f[j]);
      h[j] = r.h;
      l[j] = r.l;
    }
    *(f16x8*)(xh + idx) = h;
    *(f16x8*)(xl + idx) = l;
  } else {
    const int j = bid - 529;          // [0,256)
    const int z = j >> 6;             // matrix
    const int rem = j & 63;
    const int k0 = (rem & 7) * 64, n0 = (rem >> 3) * 64;
    const float* W = (z == 0) ? Wq : (z == 1) ? Wk : (z == 2) ? Wv : Wo;
    __shared__ float Tt[64][68];
    const int r = tid >> 2, c = (tid & 3) * 16;
#pragma unroll
    for (int jj = 0; jj < 16; jj += 4)
      *(float4*)&Tt[r][c + jj] =
          *(const float4*)(W + (size_t)(k0 + r) * EE + n0 + c + jj);
    __syncthreads();
    f16x8 h0, l0, h1, l1;
#pragma unroll
    for (int jj = 0; jj < 8; ++jj) {
      HL r0 = split16(Tt[c + jj][r]);
      HL r1 = split16(Tt[c + 8 + jj][r]);
      h0[jj] = r0.h; l0[jj] = r0.l;
      h1[jj] = r1.h; l1[jj] = r1.l;
    }
    _Float16* dh = Wth + ((size_t)z * EE + n0 + r) * EE + k0 + c;
    _Float16* dl = Wtl + ((size_t)z * EE + n0 + r) * EE + k0 + c;
    *(f16x8*)dh = h0;
    *(f16x8*)(dh + 8) = h1;
    *(f16x8*)dl = l0;
    *(f16x8*)(dl + 8) = l1;
  }
}

// ---------------------------------------------------------------------------
// K_qkv: LDS-staged 3-term f16 MFMA GEMM. Block = 64m x 64n, 4 waves stacked
// in m. q is pre-scaled by 0.125. For which==2 (V), the output tile (one head,
// 64si x 64d) is transposed in LDS and written directly as v_t hi/lo
// [bh][d][si] -- v fp32 is never materialized and k_vt is gone.
__global__ __launch_bounds__(256) void k_qkv_mfma(
    const _Float16* __restrict__ xh, const _Float16* __restrict__ xl,
    const _Float16* __restrict__ Wth, const _Float16* __restrict__ Wtl,
    const float* __restrict__ bq, const float* __restrict__ bk,
    const float* __restrict__ bv,
    _Float16* __restrict__ qh, _Float16* __restrict__ ql,
    _Float16* __restrict__ kh, _Float16* __restrict__ kl,
    _Float16* __restrict__ vth, _Float16* __restrict__ vtl) {
  const int which = blockIdx.z;
  const int tid = threadIdx.x;
  const int wave = tid >> 6, lane = tid & 63;
  const int quad = lane >> 4, l16 = lane & 15;
  const int m0 = blockIdx.y * 64;
  const int n0 = blockIdx.x * 64;
  const _Float16* Bh = Wth + (size_t)which * EE * EE;
  const _Float16* Bl = Wtl + (size_t)which * EE * EE;

  __shared__ __align__(16) char smpool[36864];
  _Float16(*LAh)[72] = (_Float16(*)[72])(smpool);
  _Float16(*LAl)[72] = (_Float16(*)[72])(smpool + 9216);
  _Float16(*LBh)[72] = (_Float16(*)[72])(smpool + 18432);
  _Float16(*LBl)[72] = (_Float16(*)[72])(smpool + 27648);
  float(*TR)[68] = (float(*)[68])(smpool);  // reused for V transpose

  const int sr0 = tid >> 3, sc0 = (tid & 7) * 8;
  const int sr1 = (tid + 256) >> 3, sc1 = sc0;

  f32x4 acc[4] = {};
  for (int k0 = 0; k0 < EE; k0 += 64) {
    if (k0) __syncthreads();
    *(f16x8*)&LAh[sr0][sc0] = *(const f16x8*)(xh + (size_t)(m0 + sr0) * EE + k0 + sc0);
    *(f16x8*)&LAl[sr0][sc0] = *(const f16x8*)(xl + (size_t)(m0 + sr0) * EE + k0 + sc0);
    *(f16x8*)&LBh[sr0][sc0] = *(const f16x8*)(Bh + (size_t)(n0 + sr0) * EE + k0 + sc0);
    *(f16x8*)&LBl[sr0][sc0] = *(const f16x8*)(Bl + (size_t)(n0 + sr0) * EE + k0 + sc0);
    *(f16x8*)&LAh[sr1][sc1] = *(const f16x8*)(xh + (size_t)(m0 + sr1) * EE + k0 + sc1);
    *(f16x8*)&LAl[sr1][sc1] = *(const f16x8*)(xl + (size_t)(m0 + sr1) * EE + k0 + sc1);
    *(f16x8*)&LBh[sr1][sc1] = *(const f16x8*)(Bh + (size_t)(n0 + sr1) * EE + k0 + sc1);
    *(f16x8*)&LBl[sr1][sc1] = *(const f16x8*)(Bl + (size_t)(n0 + sr1) * EE + k0 + sc1);
    __syncthreads();
#pragma unroll
    for (int kk = 0; kk < 64; kk += 32) {
      f16x8 ah = *(const f16x8*)&LAh[wave * 16 + l16][kk + quad * 8];
      f16x8 al = *(const f16x8*)&LAl[wave * 16 + l16][kk + quad * 8];
#pragma unroll
      for (int nt = 0; nt < 4; ++nt) {
        f16x8 bhf = *(const f16x8*)&LBh[nt * 16 + l16][kk + quad * 8];
        f16x8 blf = *(const f16x8*)&LBl[nt * 16 + l16][kk + quad * 8];
        acc[nt] = __builtin_amdgcn_mfma_f32_16x16x32_f16(ah, bhf, acc[nt], 0, 0, 0);
        acc[nt] = __builtin_amdgcn_mfma_f32_16x16x32_f16(ah, blf, acc[nt], 0, 0, 0);
        acc[nt] = __builtin_amdgcn_mfma_f32_16x16x32_f16(al, bhf, acc[nt], 0, 0, 0);
      }
    }
  }
  const float* bias = (which == 0) ? bq : (which == 1) ? bk : bv;
  if (which == 2) {
    // V path: bias-add, transpose via LDS, store split-f16 [bh][d][si]
    __syncthreads();  // main-loop LDS reads done before overwrite
#pragma unroll
    for (int nt = 0; nt < 4; ++nt) {
      const int dcol = nt * 16 + l16;             // d within head
      const float bb = bias[n0 + nt * 16 + l16];  // n0 = head*64
#pragma unroll
      for (int r = 0; r < 4; ++r)
        TR[dcol][wave * 16 + quad * 4 + r] = acc[nt][r] + bb;
    }
    __syncthreads();
    const int d = tid >> 2, cc = (tid & 3) * 16;
    const int bh = (m0 >> 9) * NH + (n0 >> 6);
    const int si0 = m0 & 511;
    f16x8 h0, l0, h1, l1;
#pragma unroll
    for (int jj = 0; jj < 8; ++jj) {
      HL r0 = split16(TR[d][cc + jj]);
      HL r1 = split16(TR[d][cc + 8 + jj]);
      h0[jj] = r0.h; l0[jj] = r0.l;
      h1[jj] = r1.h; l1[jj] = r1.l;
    }
    _Float16* dh = vth + ((size_t)bh * HD + d) * SS + si0 + cc;
    _Float16* dl = vtl + ((size_t)bh * HD + d) * SS + si0 + cc;
    *(f16x8*)dh = h0;
    *(f16x8*)(dh + 8) = h1;
    *(f16x8*)dl = l0;
    *(f16x8*)(dl + 8) = l1;
  } else {
    const float postscale = (which == 0) ? 0.125f : 1.0f;
    const int mbase = m0 + wave * 16 + quad * 4;
#pragma unroll
    for (int nt = 0; nt < 4; ++nt) {
      const int col = n0 + nt * 16 + l16;
      const float bb = bias[col];
      const int hh = col >> 6, d = col & 63;
#pragma unroll
      for (int r = 0; r < 4; ++r) {
        const int mm = mbase + r;
        const int b_ = mm >> 9, si = mm & 511;
        const size_t idx = (((size_t)(b_ * NH + hh)) * SS + si) * HD + d;
        const float val = (acc[nt][r] + bb) * postscale;
        HL sp = split16(val);
        (which ? kh : qh)[idx] = sp.h;
        (which ? kl : ql)[idx] = sp.l;
      }
    }
  }
}

// ---------------------------------------------------------------------------
// K_scores: s = clip(q.k^T, -15, 15) via 3-term f16 MFMA (q pre-scaled).
// grid (8 nTiles, 8 mTiles, 32 bh), block 256 (4 waves stacked in m).
__global__ __launch_bounds__(256) void k_scores_mfma(
    const _Float16* __restrict__ qh, const _Float16* __restrict__ ql,
    const _Float16* __restrict__ kh, const _Float16* __restrict__ kl,
    float* __restrict__ s) {
  const int bh = blockIdx.z;
  const int i0 = blockIdx.y * 64, j0 = blockIdx.x * 64;
  const int tid = threadIdx.x;
  const int wave = tid >> 6, lane = tid & 63;
  const int quad = lane >> 4, l16 = lane & 15;

  const size_t qoff = ((size_t)bh * SS + i0 + wave * 16 + l16) * HD + quad * 8;
  f16x8 a_hi[2], a_lo[2];
#pragma unroll
  for (int ks = 0; ks < 2; ++ks) {
    a_hi[ks] = *(const f16x8*)(qh + qoff + ks * 32);
    a_lo[ks] = *(const f16x8*)(ql + qoff + ks * 32);
  }
  f16x8 b_hi[4][2], b_lo[4][2];
#pragma unroll
  for (int t = 0; t < 4; ++t) {
    const size_t koff = ((size_t)bh * SS + j0 + t * 16 + l16) * HD + quad * 8;
#pragma unroll
    for (int ks = 0; ks < 2; ++ks) {
      b_hi[t][ks] = *(const f16x8*)(kh + koff + ks * 32);
      b_lo[t][ks] = *(const f16x8*)(kl + koff + ks * 32);
    }
  }
  f32x4 acc[4] = {};
#pragma unroll
  for (int ks = 0; ks < 2; ++ks) {
#pragma unroll
    for (int t = 0; t < 4; ++t) {
      acc[t] = __builtin_amdgcn_mfma_f32_16x16x32_f16(a_hi[ks], b_hi[t][ks],
                                                      acc[t], 0, 0, 0);
      acc[t] = __builtin_amdgcn_mfma_f32_16x16x32_f16(a_hi[ks], b_lo[t][ks],
                                                      acc[t], 0, 0, 0);
      acc[t] = __builtin_amdgcn_mfma_f32_16x16x32_f16(a_lo[ks], b_hi[t][ks],
                                                      acc[t], 0, 0, 0);
    }
  }
  float* sb = s + (size_t)bh * SS * SS;
#pragma unroll
  for (int t = 0; t < 4; ++t) {
#pragma unroll
    for (int r = 0; r < 4; ++r) {
      float val = clampf(acc[t][r], -15.0f, 15.0f);  // inputs finite
      sb[(size_t)(i0 + wave * 16 + quad * 4 + r) * SS + j0 + t * 16 + l16] = val;
    }
  }
}

// ---------------------------------------------------------------------------
// K_rowstat: per-row fused ma + autopoietic transform (one wave per row).
__global__ __launch_bounds__(64) void k_rowstat(
    const float* __restrict__ s, const float* __restrict__ T,
    float* __restrict__ ma, float* __restrict__ t_un,
    float* __restrict__ rowred) {
  const int row = blockIdx.x;  // b*S + i
  const int b_ = row >> 9, i = row & 511;
  const int lane = threadIdx.x;

  float4 a0 = {0.f, 0.f, 0.f, 0.f}, a1 = {0.f, 0.f, 0.f, 0.f};
#pragma unroll
  for (int hh = 0; hh < NH; ++hh) {
    const float4* p = reinterpret_cast<const float4*>(
                          s + (((size_t)(b_ * NH + hh) * SS) + i) * SS) +
                      lane * 2;
    float4 u0 = p[0], u1 = p[1];
    a0.x += u0.x; a0.y += u0.y; a0.z += u0.z; a0.w += u0.w;
    a1.x += u1.x; a1.y += u1.y; a1.z += u1.z; a1.w += u1.w;
  }
  float m[8] = {a0.x * 0.125f, a0.y * 0.125f, a0.z * 0.125f, a0.w * 0.125f,
                a1.x * 0.125f, a1.y * 0.125f, a1.z * 0.125f, a1.w * 0.125f};
  {
    float4* mp = reinterpret_cast<float4*>(ma + ((size_t)b_ * SS + i) * SS) +
                 lane * 2;
    float4 w0 = {m[0], m[1], m[2], m[3]}, w1v = {m[4], m[5], m[6], m[7]};
    mp[0] = w0;
    mp[1] = w1v;
  }
  float sma = 0.f, sma2 = 0.f, mabs = 0.f;
#pragma unroll
  for (int e = 0; e < 8; ++e) {
    sma += m[e];
    sma2 += m[e] * m[e];
    mabs = fmaxf(mabs, fabsf(m[e]));
  }
  sma = waveRedSum(sma);
  sma2 = waveRedSum(sma2);
  mabs = waveRedMax(mabs);

  float ex[8], esum = 0.f;
#pragma unroll
  for (int e = 0; e < 8; ++e) {
    ex[e] = expf(clampf(m[e], -10.f, 10.f));
    esum += ex[e];
  }
  esum = waveRedSum(esum);
  float inv = 1.0f / esum;
  float Hv[8], sH = 0.f;
#pragma unroll
  for (int e = 0; e < 8; ++e) {
    float p = ex[e] * inv;
    Hv[e] = -p * logf(p + 1e-6f);
    sH += Hv[e];
  }
  sH = waveRedSum(sH);

  float fx[8], fsum = 0.f;
#pragma unroll
  for (int e = 0; e < 8; ++e) {
    fx[e] = expf(3.0f * Hv[e]);
    fsum += fx[e];
  }
  fsum = waveRedSum(fsum);
  float finv = 1.0f / fsum;

  float t[8], st = 0.f, st2 = 0.f;
#pragma unroll
  for (int e = 0; e < 8; ++e) {
    float sa = clampf(m[e], -8.f, 8.f) * 0.05f;
    float pos = (sa + 0.4f) * ((float)NTAB / 0.8f);
    int idx = (int)pos;
    idx = idx < 0 ? 0 : (idx > NTAB - 1 ? NTAB - 1 : idx);
    float frac = pos - (float)idx;
    float g0 = T[idx], g1 = T[idx + 1];
    float sig = g0 + (g1 - g0) * frac;
    t[e] = sig * fx[e] * finv;
    st += t[e];
    st2 += t[e] * t[e];
  }
  st = waveRedSum(st);
  st2 = waveRedSum(st2);
  {
    float4* tp = reinterpret_cast<float4*>(t_un + ((size_t)b_ * SS + i) * SS) +
                 lane * 2;
    float4 w0 = {t[0], t[1], t[2], t[3]}, w1v = {t[4], t[5], t[6], t[7]};
    tp[0] = w0;
    tp[1] = w1v;
  }
  if (lane == 0) {
    float* rp = rowred + (size_t)row * 8;
    rp[0] = sma; rp[1] = sma2; rp[2] = mabs;
    rp[3] = st;  rp[4] = st2;  rp[5] = sH;
  }
}

// ---------------------------------------------------------------------------
// K_consts: reduce per-row partials -> per-batch blend constants.
__global__ __launch_bounds__(256) void k_consts(
    const float* __restrict__ rowred, float* __restrict__ cst) {
  const int b_ = blockIdx.x;
  const int tid = threadIdx.x;
  __shared__ float red[4];
  const float* r0 = rowred + ((size_t)b_ * SS + tid * 2) * 8;
  const float* r1 = r0 + 8;
  float sma = blockRedSum(r0[0] + r1[0], red);
  float sma2 = blockRedSum(r0[1] + r1[1], red);
  float mabs = blockRedMax(fmaxf(r0[2], r1[2]), red);
  float st = blockRedSum(r0[3] + r1[3], red);
  float st2 = blockRedSum(r0[4] + r1[4], red);
  float sH = blockRedSum(r0[5] + r1[5], red);
  if (tid == 0) {
    const float N = (float)(SS * SS);
    float eo = sqrtf(sma2) + 1e-4f;
    float et = sqrtf(st2) + 1e-4f;
    float r = clampf(eo / et, 0.8f, 1.2f);
    float tmean = r * st / N;
    float om = sma / N;
    float vart = r * r * fmaxf(st2 / N - (st / N) * (st / N), 0.f);
    float tstd = sqrtf(fmaxf(vart, 0.01f));
    float varo = fmaxf(sma2 / N - om * om, 0.f);
    float ostd = sqrtf(fmaxf(varo, 0.01f));
    float gd = clampf(ostd / tstd, 0.8f, 1.2f);
    float ar = clampf(mabs, 1.f, 10.f);
    float sm = clampf(0.3f / log1pf(ar), 0.1f, 0.5f);
    float ent = sH / N;
    float ne = ent / logf((float)SS);
    float rr = 0.4f * (1.f - clampf(ne, 0.f, 0.4f));
    float G = sm * gd;
    cst[b_ * 4 + 0] = rr * (1.f - G) * tmean;  // c0
    cst[b_ * 4 + 1] = rr * G * r;              // c1 (multiplies t_un)
    cst[b_ * 4 + 2] = rr;                      // c2 (multiplies ma)
  }
}

// ---------------------------------------------------------------------------
// K_rowsum: softmax denominators per (bh,i) row of the blended scores.
// One wave per row; no max-subtraction (|v| <= ~21). Writes 1/sum.
__global__ __launch_bounds__(64) void k_rowsum(
    const float* __restrict__ s, const float* __restrict__ ma,
    const float* __restrict__ t_un, const float* __restrict__ cst,
    const float* __restrict__ tau, float* __restrict__ rinv) {
  const int rid = blockIdx.x;          // bh*512 + i
  const int bh = rid >> 9, i = rid & 511;
  const int b_ = bh >> 3;
  const int lane = threadIdx.x;
  const float c0 = cst[b_ * 4 + 0], c1 = cst[b_ * 4 + 1], c2 = cst[b_ * 4 + 2];
  const float itau = 1.0f / tau[0];
  const float* srow = s + ((size_t)bh * SS + i) * SS;
  const float* mrow = ma + ((size_t)b_ * SS + i) * SS;
  const float* trow = t_un + ((size_t)b_ * SS + i) * SS;

  float sum = 0.f;
#pragma unroll
  for (int u = 0; u < 2; ++u) {
    float4 sv = ((const float4*)srow)[lane * 2 + u];
    float4 mv = ((const float4*)mrow)[lane * 2 + u];
    float4 tv = ((const float4*)trow)[lane * 2 + u];
    const float* sp = (const float*)&sv;
    const float* mp = (const float*)&mv;
    const float* tp = (const float*)&tv;
#pragma unroll
    for (int j = 0; j < 4; ++j) {
      float vv = (sp[j] + c0 + c1 * tp[j] - c2 * mp[j]) * itau;
      sum += expf(vv);
    }
  }
  sum = waveRedSum(sum);
  if (lane == 0) rinv[rid] = 1.0f / sum;
}

// ---------------------------------------------------------------------------
// K_av_fused: out = softmax(blend(s)) @ v, p computed in-register from raw s.
// Wave = 16m x 32n. grid (2 nh, 8 mb, 32 bh) = 512 blocks, 2048 waves.
__global__ __launch_bounds__(256) void k_av_fused(
    const float* __restrict__ s, const float* __restrict__ ma,
    const float* __restrict__ t_un, const float* __restrict__ cst,
    const float* __restrict__ tau, const float* __restrict__ rinv,
    const _Float16* __restrict__ vth, const _Float16* __restrict__ vtl,
    _Float16* __restrict__ oh, _Float16* __restrict__ ol) {
  const int bh = blockIdx.z;
  const int b_ = bh >> 3, hh = bh & 7;
  const int nh = blockIdx.x;           // n half: cols nh*32..nh*32+31
  const int tid = threadIdx.x;
  const int wave = tid >> 6, lane = tid & 63;
  const int quad = lane >> 4, l16 = lane & 15;
  const int m0 = blockIdx.y * 64 + wave * 16;
  const int row = m0 + l16;            // this lane's A-fragment row

  const float c0 = cst[b_ * 4 + 0], c1 = cst[b_ * 4 + 1], c2 = cst[b_ * 4 + 2];
  const float itau = 1.0f / tau[0];
  const float inv = rinv[(size_t)bh * SS + row];
  const float* srow = s + ((size_t)bh * SS + row) * SS;
  const float* mrow = ma + ((size_t)b_ * SS + row) * SS;
  const float* trow = t_un + ((size_t)b_ * SS + row) * SS;

  f32x4 acc[2] = {};
  for (int k0 = 0; k0 < SS; k0 += 32) {
    const int off = k0 + quad * 8;
    float4 s0 = *(const float4*)(srow + off);
    float4 s1 = *(const float4*)(srow + off + 4);
    float4 mv0 = *(const float4*)(mrow + off);
    float4 mv1 = *(const float4*)(mrow + off + 4);
    float4 tv0 = *(const float4*)(trow + off);
    float4 tv1 = *(const float4*)(trow + off + 4);
    float sv[8] = {s0.x, s0.y, s0.z, s0.w, s1.x, s1.y, s1.z, s1.w};
    float mvv[8] = {mv0.x, mv0.y, mv0.z, mv0.w, mv1.x, mv1.y, mv1.z, mv1.w};
    float tvv[8] = {tv0.x, tv0.y, tv0.z, tv0.w, tv1.x, tv1.y, tv1.z, tv1.w};
    f16x8 ah, al;
#pragma unroll
    for (int j = 0; j < 8; ++j) {
      float vv = (sv[j] + c0 + c1 * tvv[j] - c2 * mvv[j]) * itau;
      float p = expf(vv) * inv;
      HL r = split16(p);
      ah[j] = r.h;
      al[j] = r.l;
    }
#pragma unroll
    for (int nt = 0; nt < 2; ++nt) {
      const size_t boff =
          ((size_t)bh * HD + nh * 32 + nt * 16 + l16) * SS + k0 + quad * 8;
      f16x8 bh_ = *(const f16x8*)(vth + boff);
      f16x8 bl_ = *(const f16x8*)(vtl + boff);
      acc[nt] = __builtin_amdgcn_mfma_f32_16x16x32_f16(ah, bh_, acc[nt], 0, 0, 0);
      acc[nt] = __builtin_amdgcn_mfma_f32_16x16x32_f16(ah, bl_, acc[nt], 0, 0, 0);
      acc[nt] = __builtin_amdgcn_mfma_f32_16x16x32_f16(al, bh_, acc[nt], 0, 0, 0);
    }
  }
#pragma unroll
  for (int nt = 0; nt < 2; ++nt) {
#pragma unroll
    for (int r = 0; r < 4; ++r) {
      const int si = m0 + quad * 4 + r;
      const size_t idx = ((size_t)(b_ * SS + si)) * EE + hh * HD + nh * 32 +
                         nt * 16 + l16;
      HL sp = split16(acc[nt][r]);
      oh[idx] = sp.h;
      ol[idx] = sp.l;
    }
  }
}

// ---------------------------------------------------------------------------
// K_out: LDS-staged 3-term f16 MFMA GEMM, fp32 output + bias.
// Same structure as k_qkv_mfma. grid (8 nb, 32 mb), block 256.
__global__ __launch_bounds__(256) void k_out_mfma(
    const _Float16* __restrict__ oh, const _Float16* __restrict__ ol,
    const _Float16* __restrict__ Wth, const _Float16* __restrict__ Wtl,
    const float* __restrict__ bo, float* __restrict__ out) {
  const int tid = threadIdx.x;
  const int wave = tid >> 6, lane = tid & 63;
  const int quad = lane >> 4, l16 = lane & 15;
  const int m0 = blockIdx.y * 64;
  const int n0 = blockIdx.x * 64;
  const _Float16* Bh = Wth + (size_t)3 * EE * EE;  // Wo^T
  const _Float16* Bl = Wtl + (size_t)3 * EE * EE;

  __shared__ _Float16 LAh[64][72], LAl[64][72], LBh[64][72], LBl[64][72];

  const int sr0 = tid >> 3, sc0 = (tid & 7) * 8;
  const int sr1 = (tid + 256) >> 3, sc1 = sc0;

  f32x4 acc[4] = {};
  for (int k0 = 0; k0 < EE; k0 += 64) {
    if (k0) __syncthreads();
    *(f16x8*)&LAh[sr0][sc0] = *(const f16x8*)(oh + (size_t)(m0 + sr0) * EE + k0 + sc0);
    *(f16x8*)&LAl[sr0][sc0] = *(const f16x8*)(ol + (size_t)(m0 + sr0) * EE + k0 + sc0);
    *(f16x8*)&LBh[sr0][sc0] = *(const f16x8*)(Bh + (size_t)(n0 + sr0) * EE + k0 + sc0);
    *(f16x8*)&LBl[sr0][sc0] = *(const f16x8*)(Bl + (size_t)(n0 + sr0) * EE + k0 + sc0);
    *(f16x8*)&LAh[sr1][sc1] = *(const f16x8*)(oh + (size_t)(m0 + sr1) * EE + k0 + sc1);
    *(f16x8*)&LAl[sr1][sc1] = *(const f16x8*)(ol + (size_t)(m0 + sr1) * EE + k0 + sc1);
    *(f16x8*)&LBh[sr1][sc1] = *(const f16x8*)(Bh + (size_t)(n0 + sr1) * EE + k0 + sc1);
    *(f16x8*)&LBl[sr1][sc1] = *(const f16x8*)(Bl + (size_t)(n0 + sr1) * EE + k0 + sc1);
    __syncthreads();
#pragma unroll
    for (int kk = 0; kk < 64; kk += 32) {
      f16x8 ah = *(const f16x8*)&LAh[wave * 16 + l16][kk + quad * 8];
      f16x8 al = *(const f16x8*)&LAl[wave * 16 + l16][kk + quad * 8];
#pragma unroll
      for (int nt = 0; nt < 4; ++nt) {
        f16x8 bhf = *(const f16x8*)&LBh[nt * 16 + l16][kk + quad * 8];
        f16x8 blf = *(const f16x8*)&LBl[nt * 16 + l16][kk + quad * 8];
        acc[nt] = __builtin_amdgcn_mfma_f32_16x16x32_f16(ah, bhf, acc[nt], 0, 0, 0);
        acc[nt] = __builtin_amdgcn_mfma_f32_16x16x32_f16(ah, blf, acc[nt], 0, 0, 0);
        acc[nt] = __builtin_amdgcn_mfma_f32_16x16x32_f16(al, bhf, acc[nt], 0, 0, 0);
      }
    }
  }
  const int mbase = m0 + wave * 16 + quad * 4;
#pragma unroll
  for (int nt = 0; nt < 4; ++nt) {
    const int col = n0 + nt * 16 + l16;
    const float bb = bo[col];
#pragma unroll
    for (int r = 0; r < 4; ++r) {
      const int m = mbase + r;
      out[(size_t)m * EE + col] = acc[nt][r] + bb;
    }
  }
}

// ---------------------------------------------------------------------------
extern "C" void kernel_launch(void* const* d_in, const int* in_sizes, int n_in,
                              void* d_out, int out_size, void* d_ws,
                              size_t ws_size, hipStream_t stream) {
  const float* x = (const float*)d_in[0];
  const float* Wq = (const float*)d_in[1];
  const float* bq = (const float*)d_in[2];
  const float* Wk = (const float*)d_in[3];
  const float* bk = (const float*)d_in[4];
  const float* Wv = (const float*)d_in[5];
  const float* bv = (const float*)d_in[6];
  const float* Wo = (const float*)d_in[7];
  const float* bo = (const float*)d_in[8];
  const float* w1 = (const float*)d_in[9];
  const float* b1 = (const float*)d_in[10];
  const float* w2 = (const float*)d_in[11];
  const float* b2 = (const float*)d_in[12];
  const float* tau = (const float*)d_in[13];
  float* out = (float*)d_out;

  const size_t NX = (size_t)2048 * EE;           // 1M elems (x, o)
  const size_t NW = (size_t)4 * EE * EE;         // 1M elems (4 W's)
  const size_t NQK = (size_t)BB * NH * SS * HD;  // 1M elems

  _Float16* xh = (_Float16*)d_ws;
  _Float16* xl = xh + NX;
  _Float16* Wth = xl + NX;
  _Float16* Wtl = Wth + NW;
  _Float16* qh = Wtl + NW;
  _Float16* ql = qh + NQK;
  _Float16* kh = ql + NQK;
  _Float16* kl = kh + NQK;
  _Float16* vth = kl + NQK;
  _Float16* vtl = vth + NQK;
  float* s = (float*)(vtl + NQK);
  float* ma = s + (size_t)BB * NH * SS * SS;
  float* t_un = ma + (size_t)BB * SS * SS;
  float* T = t_un + (size_t)BB * SS * SS;
  float* rowred = T + 8192;
  float* cst = rowred + 2048 * 8;
  float* rinv = cst + 16;                        // 16384 floats
  _Float16* oh = xh;  // alias: x dead after k_qkv_mfma
  _Float16* ol = xl;

  k_prep<<<785, 256, 0, stream>>>(w1, b1, w2, b2, T, x, xh, xl, Wq, Wk, Wv, Wo,
                                  Wth, Wtl);
  k_qkv_mfma<<<dim3(8, 32, 3), 256, 0, stream>>>(xh, xl, Wth, Wtl, bq, bk, bv,
                                                 qh, ql, kh, kl, vth, vtl);
  k_scores_mfma<<<dim3(8, 8, 32), 256, 0, stream>>>(qh, ql, kh, kl, s);
  k_rowstat<<<2048, 64, 0, stream>>>(s, T, ma, t_un, rowred);
  k_consts<<<4, 256, 0, stream>>>(rowred, cst);
  k_rowsum<<<16384, 64, 0, stream>>>(s, ma, t_un, cst, tau, rinv);
  k_av_fused<<<dim3(2, 8, 32), 256, 0, stream>>>(s, ma, t_un, cst, tau, rinv,
                                                 vth, vtl, oh, ol);
  k_out_mfma<<<dim3(8, 32), 256, 0, stream>>>(oh, ol, Wth, Wtl, bo, out);
}

// Round 8
// 191.429 us; speedup vs baseline: 1.0541x; 1.0541x over previous
//
#include <hip/hip_runtime.h>
#include <math.h>

// Problem constants (fixed by setup_inputs)
#define BB 4
#define SS 512
#define EE 512
#define NH 8
#define HD 64
#define NC 128
#define NTAB 4096  // table intervals over sa in [-0.4, 0.4]

typedef _Float16 f16x8 __attribute__((ext_vector_type(8)));
typedef float f32x4 __attribute__((ext_vector_type(4)));

struct HL { _Float16 h, l; };

__device__ __forceinline__ float clampf(float v, float lo, float hi) {
  return fminf(fmaxf(v, lo), hi);
}
__device__ __forceinline__ HL split16(float x) {
  HL r;
  r.h = (_Float16)x;
  r.l = (_Float16)(x - (float)r.h);
  return r;
}

__device__ __forceinline__ float waveRedSum(float v) {
#pragma unroll
  for (int o = 32; o; o >>= 1) v += __shfl_xor(v, o);
  return v;
}
__device__ __forceinline__ float waveRedMax(float v) {
#pragma unroll
  for (int o = 32; o; o >>= 1) v = fmaxf(v, __shfl_xor(v, o));
  return v;
}
// blockDim.x == 256 (4 waves) assumed
__device__ __forceinline__ float blockRedSum(float v, float* red) {
  int tid = threadIdx.x;
  v = waveRedSum(v);
  __syncthreads();
  if ((tid & 63) == 0) red[tid >> 6] = v;
  __syncthreads();
  return red[0] + red[1] + red[2] + red[3];
}
__device__ __forceinline__ float blockRedMax(float v, float* red) {
  int tid = threadIdx.x;
  v = waveRedMax(v);
  __syncthreads();
  if ((tid & 63) == 0) red[tid >> 6] = v;
  __syncthreads();
  return fmaxf(fmaxf(red[0], red[1]), fmaxf(red[2], red[3]));
}

// ---------------------------------------------------------------------------
// K_prep: fused preprocessing (all independent):
//   blocks [0,17): sigmoid table
//   blocks [17,529): split x -> f16 hi/lo
//   blocks [529,785): transpose+split the 4 weight matrices
__global__ __launch_bounds__(256) void k_prep(
    const float* __restrict__ w1, const float* __restrict__ b1,
    const float* __restrict__ w2, const float* __restrict__ b2,
    float* __restrict__ T, const float* __restrict__ x,
    _Float16* __restrict__ xh, _Float16* __restrict__ xl,
    const float* __restrict__ Wq, const float* __restrict__ Wk,
    const float* __restrict__ Wv, const float* __restrict__ Wo,
    _Float16* __restrict__ Wth, _Float16* __restrict__ Wtl) {
  const int bid = blockIdx.x;
  const int tid = threadIdx.x;
  if (bid < 17) {
    int idx = bid * 256 + tid;
    if (idx > NTAB) return;
    float sa = -0.4f + (float)idx * (0.8f / (float)NTAB);
    float ap = 0.f;
#pragma unroll 4
    for (int c = 0; c < NC; ++c) {
      float h = fminf(fmaxf(sa * w1[c] + b1[c], 0.f), 5.f);
      ap += h * w2[c];
    }
    ap = clampf(ap + b2[0], -5.f, 5.f);
    float tay = clampf(1.0f + 0.05f * (ap * 50.0f), 0.5f, 1.5f);
    T[idx] = 1.0f / (1.0f + expf(-tay));
  } else if (bid < 529) {
    int idx = ((bid - 17) * 256 + tid) * 8;
    float4 u0 = *(const float4*)(x + idx);
    float4 u1 = *(const float4*)(x + idx + 4);
    float f[8] = {u0.x, u0.y, u0.z, u0.w, u1.x, u1.y, u1.z, u1.w};
    f16x8 h, l;
#pragma unroll
    for (int j = 0; j < 8; ++j) {
      HL r = split16(f[j]);
      h[j] = r.h;
      l[j] = r.l;
    }
    *(f16x8*)(xh + idx) = h;
    *(f16x8*)(xl + idx) = l;
  } else {
    const int j = bid - 529;          // [0,256)
    const int z = j >> 6;             // matrix
    const int rem = j & 63;
    const int k0 = (rem & 7) * 64, n0 = (rem >> 3) * 64;
    const float* W = (z == 0) ? Wq : (z == 1) ? Wk : (z == 2) ? Wv : Wo;
    __shared__ float Tt[64][68];
    const int r = tid >> 2, c = (tid & 3) * 16;
#pragma unroll
    for (int jj = 0; jj < 16; jj += 4)
      *(float4*)&Tt[r][c + jj] =
          *(const float4*)(W + (size_t)(k0 + r) * EE + n0 + c + jj);
    __syncthreads();
    f16x8 h0, l0, h1, l1;
#pragma unroll
    for (int jj = 0; jj < 8; ++jj) {
      HL r0 = split16(Tt[c + jj][r]);
      HL r1 = split16(Tt[c + 8 + jj][r]);
      h0[jj] = r0.h; l0[jj] = r0.l;
      h1[jj] = r1.h; l1[jj] = r1.l;
    }
    _Float16* dh = Wth + ((size_t)z * EE + n0 + r) * EE + k0 + c;
    _Float16* dl = Wtl + ((size_t)z * EE + n0 + r) * EE + k0 + c;
    *(f16x8*)dh = h0;
    *(f16x8*)(dh + 8) = h1;
    *(f16x8*)dl = l0;
    *(f16x8*)(dl + 8) = l1;
  }
}

// ---------------------------------------------------------------------------
// K_qkv: LDS-staged 3-term f16 MFMA GEMM. Block = 64m x 64n, 4 waves stacked
// in m. q is pre-scaled by 0.125. For which==2 (V), the output tile (one head,
// 64si x 64d) is transposed in LDS and written directly as v_t hi/lo
// [bh][d][si].
__global__ __launch_bounds__(256) void k_qkv_mfma(
    const _Float16* __restrict__ xh, const _Float16* __restrict__ xl,
    const _Float16* __restrict__ Wth, const _Float16* __restrict__ Wtl,
    const float* __restrict__ bq, const float* __restrict__ bk,
    const float* __restrict__ bv,
    _Float16* __restrict__ qh, _Float16* __restrict__ ql,
    _Float16* __restrict__ kh, _Float16* __restrict__ kl,
    _Float16* __restrict__ vth, _Float16* __restrict__ vtl) {
  const int which = blockIdx.z;
  const int tid = threadIdx.x;
  const int wave = tid >> 6, lane = tid & 63;
  const int quad = lane >> 4, l16 = lane & 15;
  const int m0 = blockIdx.y * 64;
  const int n0 = blockIdx.x * 64;
  const _Float16* Bh = Wth + (size_t)which * EE * EE;
  const _Float16* Bl = Wtl + (size_t)which * EE * EE;

  __shared__ __align__(16) char smpool[36864];
  _Float16(*LAh)[72] = (_Float16(*)[72])(smpool);
  _Float16(*LAl)[72] = (_Float16(*)[72])(smpool + 9216);
  _Float16(*LBh)[72] = (_Float16(*)[72])(smpool + 18432);
  _Float16(*LBl)[72] = (_Float16(*)[72])(smpool + 27648);
  float(*TR)[68] = (float(*)[68])(smpool);  // reused for V transpose

  const int sr0 = tid >> 3, sc0 = (tid & 7) * 8;
  const int sr1 = (tid + 256) >> 3, sc1 = sc0;

  f32x4 acc[4] = {};
  for (int k0 = 0; k0 < EE; k0 += 64) {
    if (k0) __syncthreads();
    *(f16x8*)&LAh[sr0][sc0] = *(const f16x8*)(xh + (size_t)(m0 + sr0) * EE + k0 + sc0);
    *(f16x8*)&LAl[sr0][sc0] = *(const f16x8*)(xl + (size_t)(m0 + sr0) * EE + k0 + sc0);
    *(f16x8*)&LBh[sr0][sc0] = *(const f16x8*)(Bh + (size_t)(n0 + sr0) * EE + k0 + sc0);
    *(f16x8*)&LBl[sr0][sc0] = *(const f16x8*)(Bl + (size_t)(n0 + sr0) * EE + k0 + sc0);
    *(f16x8*)&LAh[sr1][sc1] = *(const f16x8*)(xh + (size_t)(m0 + sr1) * EE + k0 + sc1);
    *(f16x8*)&LAl[sr1][sc1] = *(const f16x8*)(xl + (size_t)(m0 + sr1) * EE + k0 + sc1);
    *(f16x8*)&LBh[sr1][sc1] = *(const f16x8*)(Bh + (size_t)(n0 + sr1) * EE + k0 + sc1);
    *(f16x8*)&LBl[sr1][sc1] = *(const f16x8*)(Bl + (size_t)(n0 + sr1) * EE + k0 + sc1);
    __syncthreads();
#pragma unroll
    for (int kk = 0; kk < 64; kk += 32) {
      f16x8 ah = *(const f16x8*)&LAh[wave * 16 + l16][kk + quad * 8];
      f16x8 al = *(const f16x8*)&LAl[wave * 16 + l16][kk + quad * 8];
#pragma unroll
      for (int nt = 0; nt < 4; ++nt) {
        f16x8 bhf = *(const f16x8*)&LBh[nt * 16 + l16][kk + quad * 8];
        f16x8 blf = *(const f16x8*)&LBl[nt * 16 + l16][kk + quad * 8];
        acc[nt] = __builtin_amdgcn_mfma_f32_16x16x32_f16(ah, bhf, acc[nt], 0, 0, 0);
        acc[nt] = __builtin_amdgcn_mfma_f32_16x16x32_f16(ah, blf, acc[nt], 0, 0, 0);
        acc[nt] = __builtin_amdgcn_mfma_f32_16x16x32_f16(al, bhf, acc[nt], 0, 0, 0);
      }
    }
  }
  const float* bias = (which == 0) ? bq : (which == 1) ? bk : bv;
  if (which == 2) {
    // V path: bias-add, transpose via LDS, store split-f16 [bh][d][si]
    __syncthreads();  // main-loop LDS reads done before overwrite
#pragma unroll
    for (int nt = 0; nt < 4; ++nt) {
      const int dcol = nt * 16 + l16;             // d within head
      const float bb = bias[n0 + nt * 16 + l16];  // n0 = head*64
#pragma unroll
      for (int r = 0; r < 4; ++r)
        TR[dcol][wave * 16 + quad * 4 + r] = acc[nt][r] + bb;
    }
    __syncthreads();
    const int d = tid >> 2, cc = (tid & 3) * 16;
    const int bh = (m0 >> 9) * NH + (n0 >> 6);
    const int si0 = m0 & 511;
    f16x8 h0, l0, h1, l1;
#pragma unroll
    for (int jj = 0; jj < 8; ++jj) {
      HL r0 = split16(TR[d][cc + jj]);
      HL r1 = split16(TR[d][cc + 8 + jj]);
      h0[jj] = r0.h; l0[jj] = r0.l;
      h1[jj] = r1.h; l1[jj] = r1.l;
    }
    _Float16* dh = vth + ((size_t)bh * HD + d) * SS + si0 + cc;
    _Float16* dl = vtl + ((size_t)bh * HD + d) * SS + si0 + cc;
    *(f16x8*)dh = h0;
    *(f16x8*)(dh + 8) = h1;
    *(f16x8*)dl = l0;
    *(f16x8*)(dl + 8) = l1;
  } else {
    const float postscale = (which == 0) ? 0.125f : 1.0f;
    const int mbase = m0 + wave * 16 + quad * 4;
#pragma unroll
    for (int nt = 0; nt < 4; ++nt) {
      const int col = n0 + nt * 16 + l16;
      const float bb = bias[col];
      const int hh = col >> 6, d = col & 63;
#pragma unroll
      for (int r = 0; r < 4; ++r) {
        const int mm = mbase + r;
        const int b_ = mm >> 9, si = mm & 511;
        const size_t idx = (((size_t)(b_ * NH + hh)) * SS + si) * HD + d;
        const float val = (acc[nt][r] + bb) * postscale;
        HL sp = split16(val);
        (which ? kh : qh)[idx] = sp.h;
        (which ? kl : ql)[idx] = sp.l;
      }
    }
  }
}

// ---------------------------------------------------------------------------
// K_scores: s = clip(q.k^T, -15, 15) via 3-term f16 MFMA (q pre-scaled).
// grid (8 nTiles, 8 mTiles, 32 bh), block 256 (4 waves stacked in m).
__global__ __launch_bounds__(256) void k_scores_mfma(
    const _Float16* __restrict__ qh, const _Float16* __restrict__ ql,
    const _Float16* __restrict__ kh, const _Float16* __restrict__ kl,
    float* __restrict__ s) {
  const int bh = blockIdx.z;
  const int i0 = blockIdx.y * 64, j0 = blockIdx.x * 64;
  const int tid = threadIdx.x;
  const int wave = tid >> 6, lane = tid & 63;
  const int quad = lane >> 4, l16 = lane & 15;

  const size_t qoff = ((size_t)bh * SS + i0 + wave * 16 + l16) * HD + quad * 8;
  f16x8 a_hi[2], a_lo[2];
#pragma unroll
  for (int ks = 0; ks < 2; ++ks) {
    a_hi[ks] = *(const f16x8*)(qh + qoff + ks * 32);
    a_lo[ks] = *(const f16x8*)(ql + qoff + ks * 32);
  }
  f16x8 b_hi[4][2], b_lo[4][2];
#pragma unroll
  for (int t = 0; t < 4; ++t) {
    const size_t koff = ((size_t)bh * SS + j0 + t * 16 + l16) * HD + quad * 8;
#pragma unroll
    for (int ks = 0; ks < 2; ++ks) {
      b_hi[t][ks] = *(const f16x8*)(kh + koff + ks * 32);
      b_lo[t][ks] = *(const f16x8*)(kl + koff + ks * 32);
    }
  }
  f32x4 acc[4] = {};
#pragma unroll
  for (int ks = 0; ks < 2; ++ks) {
#pragma unroll
    for (int t = 0; t < 4; ++t) {
      acc[t] = __builtin_amdgcn_mfma_f32_16x16x32_f16(a_hi[ks], b_hi[t][ks],
                                                      acc[t], 0, 0, 0);
      acc[t] = __builtin_amdgcn_mfma_f32_16x16x32_f16(a_hi[ks], b_lo[t][ks],
                                                      acc[t], 0, 0, 0);
      acc[t] = __builtin_amdgcn_mfma_f32_16x16x32_f16(a_lo[ks], b_hi[t][ks],
                                                      acc[t], 0, 0, 0);
    }
  }
  float* sb = s + (size_t)bh * SS * SS;
#pragma unroll
  for (int t = 0; t < 4; ++t) {
#pragma unroll
    for (int r = 0; r < 4; ++r) {
      float val = clampf(acc[t][r], -15.0f, 15.0f);  // inputs finite
      sb[(size_t)(i0 + wave * 16 + quad * 4 + r) * SS + j0 + t * 16 + l16] = val;
    }
  }
}

// ---------------------------------------------------------------------------
// K_rowstat: per-row fused ma + autopoietic transform (one wave per row).
__global__ __launch_bounds__(64) void k_rowstat(
    const float* __restrict__ s, const float* __restrict__ T,
    float* __restrict__ ma, float* __restrict__ t_un,
    float* __restrict__ rowred) {
  const int row = blockIdx.x;  // b*S + i
  const int b_ = row >> 9, i = row & 511;
  const int lane = threadIdx.x;

  float4 a0 = {0.f, 0.f, 0.f, 0.f}, a1 = {0.f, 0.f, 0.f, 0.f};
#pragma unroll
  for (int hh = 0; hh < NH; ++hh) {
    const float4* p = reinterpret_cast<const float4*>(
                          s + (((size_t)(b_ * NH + hh) * SS) + i) * SS) +
                      lane * 2;
    float4 u0 = p[0], u1 = p[1];
    a0.x += u0.x; a0.y += u0.y; a0.z += u0.z; a0.w += u0.w;
    a1.x += u1.x; a1.y += u1.y; a1.z += u1.z; a1.w += u1.w;
  }
  float m[8] = {a0.x * 0.125f, a0.y * 0.125f, a0.z * 0.125f, a0.w * 0.125f,
                a1.x * 0.125f, a1.y * 0.125f, a1.z * 0.125f, a1.w * 0.125f};
  {
    float4* mp = reinterpret_cast<float4*>(ma + ((size_t)b_ * SS + i) * SS) +
                 lane * 2;
    float4 w0 = {m[0], m[1], m[2], m[3]}, w1v = {m[4], m[5], m[6], m[7]};
    mp[0] = w0;
    mp[1] = w1v;
  }
  float sma = 0.f, sma2 = 0.f, mabs = 0.f;
#pragma unroll
  for (int e = 0; e < 8; ++e) {
    sma += m[e];
    sma2 += m[e] * m[e];
    mabs = fmaxf(mabs, fabsf(m[e]));
  }
  sma = waveRedSum(sma);
  sma2 = waveRedSum(sma2);
  mabs = waveRedMax(mabs);

  float ex[8], esum = 0.f;
#pragma unroll
  for (int e = 0; e < 8; ++e) {
    ex[e] = expf(clampf(m[e], -10.f, 10.f));
    esum += ex[e];
  }
  esum = waveRedSum(esum);
  float inv = 1.0f / esum;
  float Hv[8], sH = 0.f;
#pragma unroll
  for (int e = 0; e < 8; ++e) {
    float p = ex[e] * inv;
    Hv[e] = -p * logf(p + 1e-6f);
    sH += Hv[e];
  }
  sH = waveRedSum(sH);

  float fx[8], fsum = 0.f;
#pragma unroll
  for (int e = 0; e < 8; ++e) {
    fx[e] = expf(3.0f * Hv[e]);
    fsum += fx[e];
  }
  fsum = waveRedSum(fsum);
  float finv = 1.0f / fsum;

  float t[8], st = 0.f, st2 = 0.f;
#pragma unroll
  for (int e = 0; e < 8; ++e) {
    float sa = clampf(m[e], -8.f, 8.f) * 0.05f;
    float pos = (sa + 0.4f) * ((float)NTAB / 0.8f);
    int idx = (int)pos;
    idx = idx < 0 ? 0 : (idx > NTAB - 1 ? NTAB - 1 : idx);
    float frac = pos - (float)idx;
    float g0 = T[idx], g1 = T[idx + 1];
    float sig = g0 + (g1 - g0) * frac;
    t[e] = sig * fx[e] * finv;
    st += t[e];
    st2 += t[e] * t[e];
  }
  st = waveRedSum(st);
  st2 = waveRedSum(st2);
  {
    float4* tp = reinterpret_cast<float4*>(t_un + ((size_t)b_ * SS + i) * SS) +
                 lane * 2;
    float4 w0 = {t[0], t[1], t[2], t[3]}, w1v = {t[4], t[5], t[6], t[7]};
    tp[0] = w0;
    tp[1] = w1v;
  }
  if (lane == 0) {
    float* rp = rowred + (size_t)row * 8;
    rp[0] = sma; rp[1] = sma2; rp[2] = mabs;
    rp[3] = st;  rp[4] = st2;  rp[5] = sH;
  }
}

// ---------------------------------------------------------------------------
// K_consts: reduce per-row partials -> per-batch blend constants.
__global__ __launch_bounds__(256) void k_consts(
    const float* __restrict__ rowred, float* __restrict__ cst) {
  const int b_ = blockIdx.x;
  const int tid = threadIdx.x;
  __shared__ float red[4];
  const float* r0 = rowred + ((size_t)b_ * SS + tid * 2) * 8;
  const float* r1 = r0 + 8;
  float sma = blockRedSum(r0[0] + r1[0], red);
  float sma2 = blockRedSum(r0[1] + r1[1], red);
  float mabs = blockRedMax(fmaxf(r0[2], r1[2]), red);
  float st = blockRedSum(r0[3] + r1[3], red);
  float st2 = blockRedSum(r0[4] + r1[4], red);
  float sH = blockRedSum(r0[5] + r1[5], red);
  if (tid == 0) {
    const float N = (float)(SS * SS);
    float eo = sqrtf(sma2) + 1e-4f;
    float et = sqrtf(st2) + 1e-4f;
    float r = clampf(eo / et, 0.8f, 1.2f);
    float tmean = r * st / N;
    float om = sma / N;
    float vart = r * r * fmaxf(st2 / N - (st / N) * (st / N), 0.f);
    float tstd = sqrtf(fmaxf(vart, 0.01f));
    float varo = fmaxf(sma2 / N - om * om, 0.f);
    float ostd = sqrtf(fmaxf(varo, 0.01f));
    float gd = clampf(ostd / tstd, 0.8f, 1.2f);
    float ar = clampf(mabs, 1.f, 10.f);
    float sm = clampf(0.3f / log1pf(ar), 0.1f, 0.5f);
    float ent = sH / N;
    float ne = ent / logf((float)SS);
    float rr = 0.4f * (1.f - clampf(ne, 0.f, 0.4f));
    float G = sm * gd;
    cst[b_ * 4 + 0] = rr * (1.f - G) * tmean;  // c0
    cst[b_ * 4 + 1] = rr * G * r;              // c1 (multiplies t_un)
    cst[b_ * 4 + 2] = rr;                      // c2 (multiplies ma)
  }
}

// ---------------------------------------------------------------------------
// K_blend: blend + row softmax, writing p as SPLIT F16 (ph/pl). One wave per
// (bh,i) row; no max-subtraction (|v| <= ~21, exp fits fp32). grid 16384x64.
// Same split the old k_av did in-register -- arithmetic identical, but k_av
// becomes pure load+MFMA.
__global__ __launch_bounds__(64) void k_blend(
    const float* __restrict__ s, const float* __restrict__ ma,
    const float* __restrict__ t_un, const float* __restrict__ cst,
    const float* __restrict__ tau, _Float16* __restrict__ ph,
    _Float16* __restrict__ pl) {
  const int rid = blockIdx.x;          // bh*512 + i
  const int bh = rid >> 9, i = rid & 511;
  const int b_ = bh >> 3;
  const int lane = threadIdx.x;
  const float c0 = cst[b_ * 4 + 0], c1 = cst[b_ * 4 + 1], c2 = cst[b_ * 4 + 2];
  const float itau = 1.0f / tau[0];
  const size_t rowbase = ((size_t)bh * SS + i) * SS;
  const float* srow = s + rowbase;
  const float* mrow = ma + ((size_t)b_ * SS + i) * SS;
  const float* trow = t_un + ((size_t)b_ * SS + i) * SS;

  float e[8], sum = 0.f;
#pragma unroll
  for (int u = 0; u < 2; ++u) {
    float4 sv = ((const float4*)srow)[lane * 2 + u];
    float4 mv = ((const float4*)mrow)[lane * 2 + u];
    float4 tv = ((const float4*)trow)[lane * 2 + u];
    const float* sp = (const float*)&sv;
    const float* mp = (const float*)&mv;
    const float* tp = (const float*)&tv;
#pragma unroll
    for (int j = 0; j < 4; ++j) {
      float vv = (sp[j] + c0 + c1 * tp[j] - c2 * mp[j]) * itau;
      e[u * 4 + j] = expf(vv);
      sum += e[u * 4 + j];
    }
  }
  sum = waveRedSum(sum);
  const float inv = 1.0f / sum;
  f16x8 hv, lv;
#pragma unroll
  for (int j = 0; j < 8; ++j) {
    HL r = split16(e[j] * inv);
    hv[j] = r.h;
    lv[j] = r.l;
  }
  *(f16x8*)(ph + rowbase + lane * 8) = hv;
  *(f16x8*)(pl + rowbase + lane * 8) = lv;
}

// ---------------------------------------------------------------------------
// K_av: out = p @ v via 3-term f16 MFMA; p pre-split by k_blend -- inner loop
// is pure 16B loads + MFMA. Wave = 16m x 32n. grid (2 nh, 8 mb, 32 bh).
__global__ __launch_bounds__(256) void k_av_mfma(
    const _Float16* __restrict__ ph, const _Float16* __restrict__ pl,
    const _Float16* __restrict__ vth, const _Float16* __restrict__ vtl,
    _Float16* __restrict__ oh, _Float16* __restrict__ ol) {
  const int bh = blockIdx.z;
  const int b_ = bh >> 3, hh = bh & 7;
  const int nh = blockIdx.x;           // n half: cols nh*32..nh*32+31
  const int tid = threadIdx.x;
  const int wave = tid >> 6, lane = tid & 63;
  const int quad = lane >> 4, l16 = lane & 15;
  const int m0 = blockIdx.x == blockIdx.x ? blockIdx.y * 64 + wave * 16 : 0;

  f32x4 acc[2] = {};
  for (int k0 = 0; k0 < SS; k0 += 32) {
    const size_t aoff = ((size_t)bh * SS + m0 + l16) * SS + k0 + quad * 8;
    f16x8 ah = *(const f16x8*)(ph + aoff);
    f16x8 al = *(const f16x8*)(pl + aoff);
#pragma unroll
    for (int nt = 0; nt < 2; ++nt) {
      const size_t boff =
          ((size_t)bh * HD + nh * 32 + nt * 16 + l16) * SS + k0 + quad * 8;
      f16x8 bh_ = *(const f16x8*)(vth + boff);
      f16x8 bl_ = *(const f16x8*)(vtl + boff);
      acc[nt] = __builtin_amdgcn_mfma_f32_16x16x32_f16(ah, bh_, acc[nt], 0, 0, 0);
      acc[nt] = __builtin_amdgcn_mfma_f32_16x16x32_f16(ah, bl_, acc[nt], 0, 0, 0);
      acc[nt] = __builtin_amdgcn_mfma_f32_16x16x32_f16(al, bh_, acc[nt], 0, 0, 0);
    }
  }
#pragma unroll
  for (int nt = 0; nt < 2; ++nt) {
#pragma unroll
    for (int r = 0; r < 4; ++r) {
      const int si = m0 + quad * 4 + r;
      const size_t idx = ((size_t)(b_ * SS + si)) * EE + hh * HD + nh * 32 +
                         nt * 16 + l16;
      HL sp = split16(acc[nt][r]);
      oh[idx] = sp.h;
      ol[idx] = sp.l;
    }
  }
}

// ---------------------------------------------------------------------------
// K_out: LDS-staged 3-term f16 MFMA GEMM, fp32 output + bias.
// Same structure as k_qkv_mfma. grid (8 nb, 32 mb), block 256.
__global__ __launch_bounds__(256) void k_out_mfma(
    const _Float16* __restrict__ oh, const _Float16* __restrict__ ol,
    const _Float16* __restrict__ Wth, const _Float16* __restrict__ Wtl,
    const float* __restrict__ bo, float* __restrict__ out) {
  const int tid = threadIdx.x;
  const int wave = tid >> 6, lane = tid & 63;
  const int quad = lane >> 4, l16 = lane & 15;
  const int m0 = blockIdx.y * 64;
  const int n0 = blockIdx.x * 64;
  const _Float16* Bh = Wth + (size_t)3 * EE * EE;  // Wo^T
  const _Float16* Bl = Wtl + (size_t)3 * EE * EE;

  __shared__ _Float16 LAh[64][72], LAl[64][72], LBh[64][72], LBl[64][72];

  const int sr0 = tid >> 3, sc0 = (tid & 7) * 8;
  const int sr1 = (tid + 256) >> 3, sc1 = sc0;

  f32x4 acc[4] = {};
  for (int k0 = 0; k0 < EE; k0 += 64) {
    if (k0) __syncthreads();
    *(f16x8*)&LAh[sr0][sc0] = *(const f16x8*)(oh + (size_t)(m0 + sr0) * EE + k0 + sc0);
    *(f16x8*)&LAl[sr0][sc0] = *(const f16x8*)(ol + (size_t)(m0 + sr0) * EE + k0 + sc0);
    *(f16x8*)&LBh[sr0][sc0] = *(const f16x8*)(Bh + (size_t)(n0 + sr0) * EE + k0 + sc0);
    *(f16x8*)&LBl[sr0][sc0] = *(const f16x8*)(Bl + (size_t)(n0 + sr0) * EE + k0 + sc0);
    *(f16x8*)&LAh[sr1][sc1] = *(const f16x8*)(oh + (size_t)(m0 + sr1) * EE + k0 + sc1);
    *(f16x8*)&LAl[sr1][sc1] = *(const f16x8*)(ol + (size_t)(m0 + sr1) * EE + k0 + sc1);
    *(f16x8*)&LBh[sr1][sc1] = *(const f16x8*)(Bh + (size_t)(n0 + sr1) * EE + k0 + sc1);
    *(f16x8*)&LBl[sr1][sc1] = *(const f16x8*)(Bl + (size_t)(n0 + sr1) * EE + k0 + sc1);
    __syncthreads();
#pragma unroll
    for (int kk = 0; kk < 64; kk += 32) {
      f16x8 ah = *(const f16x8*)&LAh[wave * 16 + l16][kk + quad * 8];
      f16x8 al = *(const f16x8*)&LAl[wave * 16 + l16][kk + quad * 8];
#pragma unroll
      for (int nt = 0; nt < 4; ++nt) {
        f16x8 bhf = *(const f16x8*)&LBh[nt * 16 + l16][kk + quad * 8];
        f16x8 blf = *(const f16x8*)&LBl[nt * 16 + l16][kk + quad * 8];
        acc[nt] = __builtin_amdgcn_mfma_f32_16x16x32_f16(ah, bhf, acc[nt], 0, 0, 0);
        acc[nt] = __builtin_amdgcn_mfma_f32_16x16x32_f16(ah, blf, acc[nt], 0, 0, 0);
        acc[nt] = __builtin_amdgcn_mfma_f32_16x16x32_f16(al, bhf, acc[nt], 0, 0, 0);
      }
    }
  }
  const int mbase = m0 + wave * 16 + quad * 4;
#pragma unroll
  for (int nt = 0; nt < 4; ++nt) {
    const int col = n0 + nt * 16 + l16;
    const float bb = bo[col];
#pragma unroll
    for (int r = 0; r < 4; ++r) {
      const int m = mbase + r;
      out[(size_t)m * EE + col] = acc[nt][r] + bb;
    }
  }
}

// ---------------------------------------------------------------------------
extern "C" void kernel_launch(void* const* d_in, const int* in_sizes, int n_in,
                              void* d_out, int out_size, void* d_ws,
                              size_t ws_size, hipStream_t stream) {
  const float* x = (const float*)d_in[0];
  const float* Wq = (const float*)d_in[1];
  const float* bq = (const float*)d_in[2];
  const float* Wk = (const float*)d_in[3];
  const float* bk = (const float*)d_in[4];
  const float* Wv = (const float*)d_in[5];
  const float* bv = (const float*)d_in[6];
  const float* Wo = (const float*)d_in[7];
  const float* bo = (const float*)d_in[8];
  const float* w1 = (const float*)d_in[9];
  const float* b1 = (const float*)d_in[10];
  const float* w2 = (const float*)d_in[11];
  const float* b2 = (const float*)d_in[12];
  const float* tau = (const float*)d_in[13];
  float* out = (float*)d_out;

  const size_t NX = (size_t)2048 * EE;           // 1M elems (x, o)
  const size_t NW = (size_t)4 * EE * EE;         // 1M elems (4 W's)
  const size_t NQK = (size_t)BB * NH * SS * HD;  // 1M elems
  const size_t NS = (size_t)BB * NH * SS * SS;   // 8.39M elems

  _Float16* xh = (_Float16*)d_ws;
  _Float16* xl = xh + NX;
  _Float16* Wth = xl + NX;
  _Float16* Wtl = Wth + NW;
  _Float16* qh = Wtl + NW;
  _Float16* ql = qh + NQK;
  _Float16* kh = ql + NQK;
  _Float16* kl = kh + NQK;
  _Float16* vth = kl + NQK;
  _Float16* vtl = vth + NQK;
  float* s = (float*)(vtl + NQK);
  float* ma = s + NS;
  float* t_un = ma + (size_t)BB * SS * SS;
  float* T = t_un + (size_t)BB * SS * SS;
  float* rowred = T + 8192;
  float* cst = rowred + 2048 * 8;
  _Float16* ph = (_Float16*)(cst + 16);
  _Float16* pl = ph + NS;
  _Float16* oh = xh;  // alias: x dead after k_qkv_mfma
  _Float16* ol = xl;

  k_prep<<<785, 256, 0, stream>>>(w1, b1, w2, b2, T, x, xh, xl, Wq, Wk, Wv, Wo,
                                  Wth, Wtl);
  k_qkv_mfma<<<dim3(8, 32, 3), 256, 0, stream>>>(xh, xl, Wth, Wtl, bq, bk, bv,
                                                 qh, ql, kh, kl, vth, vtl);
  k_scores_mfma<<<dim3(8, 8, 32), 256, 0, stream>>>(qh, ql, kh, kl, s);
  k_rowstat<<<2048, 64, 0, stream>>>(s, T, ma, t_un, rowred);
  k_consts<<<4, 256, 0, stream>>>(rowred, cst);
  k_blend<<<16384, 64, 0, stream>>>(s, ma, t_un, cst, tau, ph, pl);
  k_av_mfma<<<dim3(2, 8, 32), 256, 0, stream>>>(ph, pl, vth, vtl, oh, ol);
  k_out_mfma<<<dim3(8, 32), 256, 0, stream>>>(oh, ol, Wth, Wtl, bo, out);
}

// Round 9
// 171.348 us; speedup vs baseline: 1.1776x; 1.1172x over previous
//
#include <hip/hip_runtime.h>
#include <math.h>

// Problem constants (fixed by setup_inputs)
#define BB 4
#define SS 512
#define EE 512
#define NH 8
#define HD 64
#define NC 128
#define NTAB 4096  // table intervals over sa in [-0.4, 0.4]

typedef _Float16 f16x8 __attribute__((ext_vector_type(8)));
typedef float f32x4 __attribute__((ext_vector_type(4)));

struct HL { _Float16 h, l; };

__device__ __forceinline__ float clampf(float v, float lo, float hi) {
  return fminf(fmaxf(v, lo), hi);
}
__device__ __forceinline__ HL split16(float x) {
  HL r;
  r.h = (_Float16)x;
  r.l = (_Float16)(x - (float)r.h);
  return r;
}

__device__ __forceinline__ float waveRedSum(float v) {
#pragma unroll
  for (int o = 32; o; o >>= 1) v += __shfl_xor(v, o);
  return v;
}
__device__ __forceinline__ float waveRedMax(float v) {
#pragma unroll
  for (int o = 32; o; o >>= 1) v = fmaxf(v, __shfl_xor(v, o));
  return v;
}
// blockDim.x == 256 (4 waves) assumed
__device__ __forceinline__ float blockRedSum(float v, float* red) {
  int tid = threadIdx.x;
  v = waveRedSum(v);
  __syncthreads();
  if ((tid & 63) == 0) red[tid >> 6] = v;
  __syncthreads();
  return red[0] + red[1] + red[2] + red[3];
}
__device__ __forceinline__ float blockRedMax(float v, float* red) {
  int tid = threadIdx.x;
  v = waveRedMax(v);
  __syncthreads();
  if ((tid & 63) == 0) red[tid >> 6] = v;
  __syncthreads();
  return fmaxf(fmaxf(red[0], red[1]), fmaxf(red[2], red[3]));
}

// ---------------------------------------------------------------------------
// K_prep: fused preprocessing (all independent):
//   blocks [0,17): sigmoid table
//   blocks [17,529): split x -> f16 hi/lo
//   blocks [529,785): transpose+split the 4 weight matrices
__global__ __launch_bounds__(256) void k_prep(
    const float* __restrict__ w1, const float* __restrict__ b1,
    const float* __restrict__ w2, const float* __restrict__ b2,
    float* __restrict__ T, const float* __restrict__ x,
    _Float16* __restrict__ xh, _Float16* __restrict__ xl,
    const float* __restrict__ Wq, const float* __restrict__ Wk,
    const float* __restrict__ Wv, const float* __restrict__ Wo,
    _Float16* __restrict__ Wth, _Float16* __restrict__ Wtl) {
  const int bid = blockIdx.x;
  const int tid = threadIdx.x;
  if (bid < 17) {
    int idx = bid * 256 + tid;
    if (idx > NTAB) return;
    float sa = -0.4f + (float)idx * (0.8f / (float)NTAB);
    float ap = 0.f;
#pragma unroll 4
    for (int c = 0; c < NC; ++c) {
      float h = fminf(fmaxf(sa * w1[c] + b1[c], 0.f), 5.f);
      ap += h * w2[c];
    }
    ap = clampf(ap + b2[0], -5.f, 5.f);
    float tay = clampf(1.0f + 0.05f * (ap * 50.0f), 0.5f, 1.5f);
    T[idx] = 1.0f / (1.0f + expf(-tay));
  } else if (bid < 529) {
    int idx = ((bid - 17) * 256 + tid) * 8;
    float4 u0 = *(const float4*)(x + idx);
    float4 u1 = *(const float4*)(x + idx + 4);
    float f[8] = {u0.x, u0.y, u0.z, u0.w, u1.x, u1.y, u1.z, u1.w};
    f16x8 h, l;
#pragma unroll
    for (int j = 0; j < 8; ++j) {
      HL r = split16(f[j]);
      h[j] = r.h;
      l[j] = r.l;
    }
    *(f16x8*)(xh + idx) = h;
    *(f16x8*)(xl + idx) = l;
  } else {
    const int j = bid - 529;          // [0,256)
    const int z = j >> 6;             // matrix
    const int rem = j & 63;
    const int k0 = (rem & 7) * 64, n0 = (rem >> 3) * 64;
    const float* W = (z == 0) ? Wq : (z == 1) ? Wk : (z == 2) ? Wv : Wo;
    __shared__ float Tt[64][68];
    const int r = tid >> 2, c = (tid & 3) * 16;
#pragma unroll
    for (int jj = 0; jj < 16; jj += 4)
      *(float4*)&Tt[r][c + jj] =
          *(const float4*)(W + (size_t)(k0 + r) * EE + n0 + c + jj);
    __syncthreads();
    f16x8 h0, l0, h1, l1;
#pragma unroll
    for (int jj = 0; jj < 8; ++jj) {
      HL r0 = split16(Tt[c + jj][r]);
      HL r1 = split16(Tt[c + 8 + jj][r]);
      h0[jj] = r0.h; l0[jj] = r0.l;
      h1[jj] = r1.h; l1[jj] = r1.l;
    }
    _Float16* dh = Wth + ((size_t)z * EE + n0 + r) * EE + k0 + c;
    _Float16* dl = Wtl + ((size_t)z * EE + n0 + r) * EE + k0 + c;
    *(f16x8*)dh = h0;
    *(f16x8*)(dh + 8) = h1;
    *(f16x8*)dl = l0;
    *(f16x8*)(dl + 8) = l1;
  }
}

// ---------------------------------------------------------------------------
// K_qkv: LDS-staged 3-term f16 MFMA GEMM. Block = 64m x 64n, 4 waves stacked
// in m. q is pre-scaled by 0.125. For which==2 (V), the output tile (one head,
// 64si x 64d) is transposed in LDS and written directly as v_t hi/lo
// [bh][d][si].
__global__ __launch_bounds__(256) void k_qkv_mfma(
    const _Float16* __restrict__ xh, const _Float16* __restrict__ xl,
    const _Float16* __restrict__ Wth, const _Float16* __restrict__ Wtl,
    const float* __restrict__ bq, const float* __restrict__ bk,
    const float* __restrict__ bv,
    _Float16* __restrict__ qh, _Float16* __restrict__ ql,
    _Float16* __restrict__ kh, _Float16* __restrict__ kl,
    _Float16* __restrict__ vth, _Float16* __restrict__ vtl) {
  const int which = blockIdx.z;
  const int tid = threadIdx.x;
  const int wave = tid >> 6, lane = tid & 63;
  const int quad = lane >> 4, l16 = lane & 15;
  const int m0 = blockIdx.y * 64;
  const int n0 = blockIdx.x * 64;
  const _Float16* Bh = Wth + (size_t)which * EE * EE;
  const _Float16* Bl = Wtl + (size_t)which * EE * EE;

  __shared__ __align__(16) char smpool[36864];
  _Float16(*LAh)[72] = (_Float16(*)[72])(smpool);
  _Float16(*LAl)[72] = (_Float16(*)[72])(smpool + 9216);
  _Float16(*LBh)[72] = (_Float16(*)[72])(smpool + 18432);
  _Float16(*LBl)[72] = (_Float16(*)[72])(smpool + 27648);
  float(*TR)[68] = (float(*)[68])(smpool);  // reused for V transpose

  const int sr0 = tid >> 3, sc0 = (tid & 7) * 8;
  const int sr1 = (tid + 256) >> 3, sc1 = sc0;

  f32x4 acc[4] = {};
  for (int k0 = 0; k0 < EE; k0 += 64) {
    if (k0) __syncthreads();
    *(f16x8*)&LAh[sr0][sc0] = *(const f16x8*)(xh + (size_t)(m0 + sr0) * EE + k0 + sc0);
    *(f16x8*)&LAl[sr0][sc0] = *(const f16x8*)(xl + (size_t)(m0 + sr0) * EE + k0 + sc0);
    *(f16x8*)&LBh[sr0][sc0] = *(const f16x8*)(Bh + (size_t)(n0 + sr0) * EE + k0 + sc0);
    *(f16x8*)&LBl[sr0][sc0] = *(const f16x8*)(Bl + (size_t)(n0 + sr0) * EE + k0 + sc0);
    *(f16x8*)&LAh[sr1][sc1] = *(const f16x8*)(xh + (size_t)(m0 + sr1) * EE + k0 + sc1);
    *(f16x8*)&LAl[sr1][sc1] = *(const f16x8*)(xl + (size_t)(m0 + sr1) * EE + k0 + sc1);
    *(f16x8*)&LBh[sr1][sc1] = *(const f16x8*)(Bh + (size_t)(n0 + sr1) * EE + k0 + sc1);
    *(f16x8*)&LBl[sr1][sc1] = *(const f16x8*)(Bl + (size_t)(n0 + sr1) * EE + k0 + sc1);
    __syncthreads();
#pragma unroll
    for (int kk = 0; kk < 64; kk += 32) {
      f16x8 ah = *(const f16x8*)&LAh[wave * 16 + l16][kk + quad * 8];
      f16x8 al = *(const f16x8*)&LAl[wave * 16 + l16][kk + quad * 8];
#pragma unroll
      for (int nt = 0; nt < 4; ++nt) {
        f16x8 bhf = *(const f16x8*)&LBh[nt * 16 + l16][kk + quad * 8];
        f16x8 blf = *(const f16x8*)&LBl[nt * 16 + l16][kk + quad * 8];
        acc[nt] = __builtin_amdgcn_mfma_f32_16x16x32_f16(ah, bhf, acc[nt], 0, 0, 0);
        acc[nt] = __builtin_amdgcn_mfma_f32_16x16x32_f16(ah, blf, acc[nt], 0, 0, 0);
        acc[nt] = __builtin_amdgcn_mfma_f32_16x16x32_f16(al, bhf, acc[nt], 0, 0, 0);
      }
    }
  }
  const float* bias = (which == 0) ? bq : (which == 1) ? bk : bv;
  if (which == 2) {
    // V path: bias-add, transpose via LDS, store split-f16 [bh][d][si]
    __syncthreads();  // main-loop LDS reads done before overwrite
#pragma unroll
    for (int nt = 0; nt < 4; ++nt) {
      const int dcol = nt * 16 + l16;             // d within head
      const float bb = bias[n0 + nt * 16 + l16];  // n0 = head*64
#pragma unroll
      for (int r = 0; r < 4; ++r)
        TR[dcol][wave * 16 + quad * 4 + r] = acc[nt][r] + bb;
    }
    __syncthreads();
    const int d = tid >> 2, cc = (tid & 3) * 16;
    const int bh = (m0 >> 9) * NH + (n0 >> 6);
    const int si0 = m0 & 511;
    f16x8 h0, l0, h1, l1;
#pragma unroll
    for (int jj = 0; jj < 8; ++jj) {
      HL r0 = split16(TR[d][cc + jj]);
      HL r1 = split16(TR[d][cc + 8 + jj]);
      h0[jj] = r0.h; l0[jj] = r0.l;
      h1[jj] = r1.h; l1[jj] = r1.l;
    }
    _Float16* dh = vth + ((size_t)bh * HD + d) * SS + si0 + cc;
    _Float16* dl = vtl + ((size_t)bh * HD + d) * SS + si0 + cc;
    *(f16x8*)dh = h0;
    *(f16x8*)(dh + 8) = h1;
    *(f16x8*)dl = l0;
    *(f16x8*)(dl + 8) = l1;
  } else {
    const float postscale = (which == 0) ? 0.125f : 1.0f;
    const int mbase = m0 + wave * 16 + quad * 4;
#pragma unroll
    for (int nt = 0; nt < 4; ++nt) {
      const int col = n0 + nt * 16 + l16;
      const float bb = bias[col];
      const int hh = col >> 6, d = col & 63;
#pragma unroll
      for (int r = 0; r < 4; ++r) {
        const int mm = mbase + r;
        const int b_ = mm >> 9, si = mm & 511;
        const size_t idx = (((size_t)(b_ * NH + hh)) * SS + si) * HD + d;
        const float val = (acc[nt][r] + bb) * postscale;
        HL sp = split16(val);
        (which ? kh : qh)[idx] = sp.h;
        (which ? kl : ql)[idx] = sp.l;
      }
    }
  }
}

// ---------------------------------------------------------------------------
// K_scores: s = clip(q.k^T, -15, 15) via 3-term f16 MFMA (q pre-scaled).
// LDS-staged: Q and K 64-row tiles staged once per block, then pure
// ds_read+MFMA. grid (8 jT, 8 iT, 32 bh), block 256 (4 waves stacked in m).
__global__ __launch_bounds__(256) void k_scores_mfma(
    const _Float16* __restrict__ qh, const _Float16* __restrict__ ql,
    const _Float16* __restrict__ kh, const _Float16* __restrict__ kl,
    float* __restrict__ s) {
  const int bh = blockIdx.z;
  const int i0 = blockIdx.y * 64, j0 = blockIdx.x * 64;
  const int tid = threadIdx.x;
  const int wave = tid >> 6, lane = tid & 63;
  const int quad = lane >> 4, l16 = lane & 15;

  __shared__ _Float16 Qh[64][72], Ql[64][72], Kh[64][72], Kl[64][72];
  // stage: thread t -> row r = t>>2, cols c..c+15 (two f16x8 per array)
  const int r = tid >> 2, c = (tid & 3) * 16;
  {
    const size_t qoff = ((size_t)bh * SS + i0 + r) * HD + c;
    const size_t koff = ((size_t)bh * SS + j0 + r) * HD + c;
    *(f16x8*)&Qh[r][c] = *(const f16x8*)(qh + qoff);
    *(f16x8*)&Qh[r][c + 8] = *(const f16x8*)(qh + qoff + 8);
    *(f16x8*)&Ql[r][c] = *(const f16x8*)(ql + qoff);
    *(f16x8*)&Ql[r][c + 8] = *(const f16x8*)(ql + qoff + 8);
    *(f16x8*)&Kh[r][c] = *(const f16x8*)(kh + koff);
    *(f16x8*)&Kh[r][c + 8] = *(const f16x8*)(kh + koff + 8);
    *(f16x8*)&Kl[r][c] = *(const f16x8*)(kl + koff);
    *(f16x8*)&Kl[r][c + 8] = *(const f16x8*)(kl + koff + 8);
  }
  __syncthreads();

  f16x8 a_hi[2], a_lo[2];
#pragma unroll
  for (int ks = 0; ks < 2; ++ks) {
    a_hi[ks] = *(const f16x8*)&Qh[wave * 16 + l16][ks * 32 + quad * 8];
    a_lo[ks] = *(const f16x8*)&Ql[wave * 16 + l16][ks * 32 + quad * 8];
  }
  f32x4 acc[4] = {};
#pragma unroll
  for (int ks = 0; ks < 2; ++ks) {
#pragma unroll
    for (int t = 0; t < 4; ++t) {
      f16x8 b_hi = *(const f16x8*)&Kh[t * 16 + l16][ks * 32 + quad * 8];
      f16x8 b_lo = *(const f16x8*)&Kl[t * 16 + l16][ks * 32 + quad * 8];
      acc[t] = __builtin_amdgcn_mfma_f32_16x16x32_f16(a_hi[ks], b_hi,
                                                      acc[t], 0, 0, 0);
      acc[t] = __builtin_amdgcn_mfma_f32_16x16x32_f16(a_hi[ks], b_lo,
                                                      acc[t], 0, 0, 0);
      acc[t] = __builtin_amdgcn_mfma_f32_16x16x32_f16(a_lo[ks], b_hi,
                                                      acc[t], 0, 0, 0);
    }
  }
  float* sb = s + (size_t)bh * SS * SS;
#pragma unroll
  for (int t = 0; t < 4; ++t) {
#pragma unroll
    for (int r2 = 0; r2 < 4; ++r2) {
      float val = clampf(acc[t][r2], -15.0f, 15.0f);  // inputs finite
      sb[(size_t)(i0 + wave * 16 + quad * 4 + r2) * SS + j0 + t * 16 + l16] = val;
    }
  }
}

// ---------------------------------------------------------------------------
// K_rowstat: per-row fused ma + autopoietic transform (one wave per row).
__global__ __launch_bounds__(64) void k_rowstat(
    const float* __restrict__ s, const float* __restrict__ T,
    float* __restrict__ ma, float* __restrict__ t_un,
    float* __restrict__ rowred) {
  const int row = blockIdx.x;  // b*S + i
  const int b_ = row >> 9, i = row & 511;
  const int lane = threadIdx.x;

  float4 a0 = {0.f, 0.f, 0.f, 0.f}, a1 = {0.f, 0.f, 0.f, 0.f};
#pragma unroll
  for (int hh = 0; hh < NH; ++hh) {
    const float4* p = reinterpret_cast<const float4*>(
                          s + (((size_t)(b_ * NH + hh) * SS) + i) * SS) +
                      lane * 2;
    float4 u0 = p[0], u1 = p[1];
    a0.x += u0.x; a0.y += u0.y; a0.z += u0.z; a0.w += u0.w;
    a1.x += u1.x; a1.y += u1.y; a1.z += u1.z; a1.w += u1.w;
  }
  float m[8] = {a0.x * 0.125f, a0.y * 0.125f, a0.z * 0.125f, a0.w * 0.125f,
                a1.x * 0.125f, a1.y * 0.125f, a1.z * 0.125f, a1.w * 0.125f};
  {
    float4* mp = reinterpret_cast<float4*>(ma + ((size_t)b_ * SS + i) * SS) +
                 lane * 2;
    float4 w0 = {m[0], m[1], m[2], m[3]}, w1v = {m[4], m[5], m[6], m[7]};
    mp[0] = w0;
    mp[1] = w1v;
  }
  float sma = 0.f, sma2 = 0.f, mabs = 0.f;
#pragma unroll
  for (int e = 0; e < 8; ++e) {
    sma += m[e];
    sma2 += m[e] * m[e];
    mabs = fmaxf(mabs, fabsf(m[e]));
  }
  sma = waveRedSum(sma);
  sma2 = waveRedSum(sma2);
  mabs = waveRedMax(mabs);

  float ex[8], esum = 0.f;
#pragma unroll
  for (int e = 0; e < 8; ++e) {
    ex[e] = expf(clampf(m[e], -10.f, 10.f));
    esum += ex[e];
  }
  esum = waveRedSum(esum);
  float inv = 1.0f / esum;
  float Hv[8], sH = 0.f;
#pragma unroll
  for (int e = 0; e < 8; ++e) {
    float p = ex[e] * inv;
    Hv[e] = -p * logf(p + 1e-6f);
    sH += Hv[e];
  }
  sH = waveRedSum(sH);

  float fx[8], fsum = 0.f;
#pragma unroll
  for (int e = 0; e < 8; ++e) {
    fx[e] = expf(3.0f * Hv[e]);
    fsum += fx[e];
  }
  fsum = waveRedSum(fsum);
  float finv = 1.0f / fsum;

  float t[8], st = 0.f, st2 = 0.f;
#pragma unroll
  for (int e = 0; e < 8; ++e) {
    float sa = clampf(m[e], -8.f, 8.f) * 0.05f;
    float pos = (sa + 0.4f) * ((float)NTAB / 0.8f);
    int idx = (int)pos;
    idx = idx < 0 ? 0 : (idx > NTAB - 1 ? NTAB - 1 : idx);
    float frac = pos - (float)idx;
    float g0 = T[idx], g1 = T[idx + 1];
    float sig = g0 + (g1 - g0) * frac;
    t[e] = sig * fx[e] * finv;
    st += t[e];
    st2 += t[e] * t[e];
  }
  st = waveRedSum(st);
  st2 = waveRedSum(st2);
  {
    float4* tp = reinterpret_cast<float4*>(t_un + ((size_t)b_ * SS + i) * SS) +
                 lane * 2;
    float4 w0 = {t[0], t[1], t[2], t[3]}, w1v = {t[4], t[5], t[6], t[7]};
    tp[0] = w0;
    tp[1] = w1v;
  }
  if (lane == 0) {
    float* rp = rowred + (size_t)row * 8;
    rp[0] = sma; rp[1] = sma2; rp[2] = mabs;
    rp[3] = st;  rp[4] = st2;  rp[5] = sH;
  }
}

// ---------------------------------------------------------------------------
// K_consts: reduce per-row partials -> per-batch blend constants.
__global__ __launch_bounds__(256) void k_consts(
    const float* __restrict__ rowred, float* __restrict__ cst) {
  const int b_ = blockIdx.x;
  const int tid = threadIdx.x;
  __shared__ float red[4];
  const float* r0 = rowred + ((size_t)b_ * SS + tid * 2) * 8;
  const float* r1 = r0 + 8;
  float sma = blockRedSum(r0[0] + r1[0], red);
  float sma2 = blockRedSum(r0[1] + r1[1], red);
  float mabs = blockRedMax(fmaxf(r0[2], r1[2]), red);
  float st = blockRedSum(r0[3] + r1[3], red);
  float st2 = blockRedSum(r0[4] + r1[4], red);
  float sH = blockRedSum(r0[5] + r1[5], red);
  if (tid == 0) {
    const float N = (float)(SS * SS);
    float eo = sqrtf(sma2) + 1e-4f;
    float et = sqrtf(st2) + 1e-4f;
    float r = clampf(eo / et, 0.8f, 1.2f);
    float tmean = r * st / N;
    float om = sma / N;
    float vart = r * r * fmaxf(st2 / N - (st / N) * (st / N), 0.f);
    float tstd = sqrtf(fmaxf(vart, 0.01f));
    float varo = fmaxf(sma2 / N - om * om, 0.f);
    float ostd = sqrtf(fmaxf(varo, 0.01f));
    float gd = clampf(ostd / tstd, 0.8f, 1.2f);
    float ar = clampf(mabs, 1.f, 10.f);
    float sm = clampf(0.3f / log1pf(ar), 0.1f, 0.5f);
    float ent = sH / N;
    float ne = ent / logf((float)SS);
    float rr = 0.4f * (1.f - clampf(ne, 0.f, 0.4f));
    float G = sm * gd;
    cst[b_ * 4 + 0] = rr * (1.f - G) * tmean;  // c0
    cst[b_ * 4 + 1] = rr * G * r;              // c1 (multiplies t_un)
    cst[b_ * 4 + 2] = rr;                      // c2 (multiplies ma)
  }
}

// ---------------------------------------------------------------------------
// K_blend: blend + row softmax, writing p as SPLIT F16 (ph/pl). One wave per
// (bh,i) row; no max-subtraction (|v| <= ~21, exp fits fp32). grid 16384x64.
__global__ __launch_bounds__(64) void k_blend(
    const float* __restrict__ s, const float* __restrict__ ma,
    const float* __restrict__ t_un, const float* __restrict__ cst,
    const float* __restrict__ tau, _Float16* __restrict__ ph,
    _Float16* __restrict__ pl) {
  const int rid = blockIdx.x;          // bh*512 + i
  const int bh = rid >> 9, i = rid & 511;
  const int b_ = bh >> 3;
  const int lane = threadIdx.x;
  const float c0 = cst[b_ * 4 + 0], c1 = cst[b_ * 4 + 1], c2 = cst[b_ * 4 + 2];
  const float itau = 1.0f / tau[0];
  const size_t rowbase = ((size_t)bh * SS + i) * SS;
  const float* srow = s + rowbase;
  const float* mrow = ma + ((size_t)b_ * SS + i) * SS;
  const float* trow = t_un + ((size_t)b_ * SS + i) * SS;

  float e[8], sum = 0.f;
#pragma unroll
  for (int u = 0; u < 2; ++u) {
    float4 sv = ((const float4*)srow)[lane * 2 + u];
    float4 mv = ((const float4*)mrow)[lane * 2 + u];
    float4 tv = ((const float4*)trow)[lane * 2 + u];
    const float* sp = (const float*)&sv;
    const float* mp = (const float*)&mv;
    const float* tp = (const float*)&tv;
#pragma unroll
    for (int j = 0; j < 4; ++j) {
      float vv = (sp[j] + c0 + c1 * tp[j] - c2 * mp[j]) * itau;
      e[u * 4 + j] = expf(vv);
      sum += e[u * 4 + j];
    }
  }
  sum = waveRedSum(sum);
  const float inv = 1.0f / sum;
  f16x8 hv, lv;
#pragma unroll
  for (int j = 0; j < 8; ++j) {
    HL r = split16(e[j] * inv);
    hv[j] = r.h;
    lv[j] = r.l;
  }
  *(f16x8*)(ph + rowbase + lane * 8) = hv;
  *(f16x8*)(pl + rowbase + lane * 8) = lv;
}

// ---------------------------------------------------------------------------
// K_av: out = p @ v via 3-term f16 MFMA. Block = (mb, bh): 64m x 64n (full
// head). Per k0=32, the p-tile [64m][32k] hi/lo is staged in LDS (shared by
// all 4 waves -> p read ONCE from global), register-double-buffered so the
// global load latency overlaps MFMA. Wave w covers d-cols [16w, 16w+16).
// grid (8 mb, 32 bh), block 256.
__global__ __launch_bounds__(256) void k_av_mfma(
    const _Float16* __restrict__ ph, const _Float16* __restrict__ pl,
    const _Float16* __restrict__ vth, const _Float16* __restrict__ vtl,
    _Float16* __restrict__ oh, _Float16* __restrict__ ol) {
  const int bh = blockIdx.y;
  const int b_ = bh >> 3, hh = bh & 7;
  const int m0 = blockIdx.x * 64;
  const int tid = threadIdx.x;
  const int wave = tid >> 6, lane = tid & 63;
  const int quad = lane >> 4, l16 = lane & 15;

  __shared__ _Float16 Ph[64][40], Pl[64][40];
  const int srow = tid >> 2, schunk = (tid & 3) * 8;  // stage coords
  const size_t pbase = ((size_t)bh * SS + m0 + srow) * SS + schunk;

  f16x8 rh = *(const f16x8*)(ph + pbase);
  f16x8 rl = *(const f16x8*)(pl + pbase);

  f32x4 acc[4] = {};
  for (int k0 = 0; k0 < SS; k0 += 32) {
    if (k0) __syncthreads();  // prior-stage LDS reads done
    *(f16x8*)&Ph[srow][schunk] = rh;
    *(f16x8*)&Pl[srow][schunk] = rl;
    __syncthreads();
    if (k0 + 32 < SS) {
      rh = *(const f16x8*)(ph + pbase + k0 + 32);
      rl = *(const f16x8*)(pl + pbase + k0 + 32);
    }
    const size_t boff = ((size_t)bh * HD + wave * 16 + l16) * SS + k0 + quad * 8;
    f16x8 bh_ = *(const f16x8*)(vth + boff);
    f16x8 bl_ = *(const f16x8*)(vtl + boff);
#pragma unroll
    for (int mt = 0; mt < 4; ++mt) {
      f16x8 ah = *(const f16x8*)&Ph[mt * 16 + l16][quad * 8];
      f16x8 al = *(const f16x8*)&Pl[mt * 16 + l16][quad * 8];
      acc[mt] = __builtin_amdgcn_mfma_f32_16x16x32_f16(ah, bh_, acc[mt], 0, 0, 0);
      acc[mt] = __builtin_amdgcn_mfma_f32_16x16x32_f16(ah, bl_, acc[mt], 0, 0, 0);
      acc[mt] = __builtin_amdgcn_mfma_f32_16x16x32_f16(al, bh_, acc[mt], 0, 0, 0);
    }
  }
#pragma unroll
  for (int mt = 0; mt < 4; ++mt) {
#pragma unroll
    for (int r = 0; r < 4; ++r) {
      const int si = m0 + mt * 16 + quad * 4 + r;
      const size_t idx =
          ((size_t)(b_ * SS + si)) * EE + hh * HD + wave * 16 + l16;
      HL sp = split16(acc[mt][r]);
      oh[idx] = sp.h;
      ol[idx] = sp.l;
    }
  }
}

// ---------------------------------------------------------------------------
// K_out: LDS-staged 3-term f16 MFMA GEMM, fp32 output + bias.
// Same structure as k_qkv_mfma. grid (8 nb, 32 mb), block 256.
__global__ __launch_bounds__(256) void k_out_mfma(
    const _Float16* __restrict__ oh, const _Float16* __restrict__ ol,
    const _Float16* __restrict__ Wth, const _Float16* __restrict__ Wtl,
    const float* __restrict__ bo, float* __restrict__ out) {
  const int tid = threadIdx.x;
  const int wave = tid >> 6, lane = tid & 63;
  const int quad = lane >> 4, l16 = lane & 15;
  const int m0 = blockIdx.y * 64;
  const int n0 = blockIdx.x * 64;
  const _Float16* Bh = Wth + (size_t)3 * EE * EE;  // Wo^T
  const _Float16* Bl = Wtl + (size_t)3 * EE * EE;

  __shared__ _Float16 LAh[64][72], LAl[64][72], LBh[64][72], LBl[64][72];

  const int sr0 = tid >> 3, sc0 = (tid & 7) * 8;
  const int sr1 = (tid + 256) >> 3, sc1 = sc0;

  f32x4 acc[4] = {};
  for (int k0 = 0; k0 < EE; k0 += 64) {
    if (k0) __syncthreads();
    *(f16x8*)&LAh[sr0][sc0] = *(const f16x8*)(oh + (size_t)(m0 + sr0) * EE + k0 + sc0);
    *(f16x8*)&LAl[sr0][sc0] = *(const f16x8*)(ol + (size_t)(m0 + sr0) * EE + k0 + sc0);
    *(f16x8*)&LBh[sr0][sc0] = *(const f16x8*)(Bh + (size_t)(n0 + sr0) * EE + k0 + sc0);
    *(f16x8*)&LBl[sr0][sc0] = *(const f16x8*)(Bl + (size_t)(n0 + sr0) * EE + k0 + sc0);
    *(f16x8*)&LAh[sr1][sc1] = *(const f16x8*)(oh + (size_t)(m0 + sr1) * EE + k0 + sc1);
    *(f16x8*)&LAl[sr1][sc1] = *(const f16x8*)(ol + (size_t)(m0 + sr1) * EE + k0 + sc1);
    *(f16x8*)&LBh[sr1][sc1] = *(const f16x8*)(Bh + (size_t)(n0 + sr1) * EE + k0 + sc1);
    *(f16x8*)&LBl[sr1][sc1] = *(const f16x8*)(Bl + (size_t)(n0 + sr1) * EE + k0 + sc1);
    __syncthreads();
#pragma unroll
    for (int kk = 0; kk < 64; kk += 32) {
      f16x8 ah = *(const f16x8*)&LAh[wave * 16 + l16][kk + quad * 8];
      f16x8 al = *(const f16x8*)&LAl[wave * 16 + l16][kk + quad * 8];
#pragma unroll
      for (int nt = 0; nt < 4; ++nt) {
        f16x8 bhf = *(const f16x8*)&LBh[nt * 16 + l16][kk + quad * 8];
        f16x8 blf = *(const f16x8*)&LBl[nt * 16 + l16][kk + quad * 8];
        acc[nt] = __builtin_amdgcn_mfma_f32_16x16x32_f16(ah, bhf, acc[nt], 0, 0, 0);
        acc[nt] = __builtin_amdgcn_mfma_f32_16x16x32_f16(ah, blf, acc[nt], 0, 0, 0);
        acc[nt] = __builtin_amdgcn_mfma_f32_16x16x32_f16(al, bhf, acc[nt], 0, 0, 0);
      }
    }
  }
  const int mbase = m0 + wave * 16 + quad * 4;
#pragma unroll
  for (int nt = 0; nt < 4; ++nt) {
    const int col = n0 + nt * 16 + l16;
    const float bb = bo[col];
#pragma unroll
    for (int r = 0; r < 4; ++r) {
      const int m = mbase + r;
      out[(size_t)m * EE + col] = acc[nt][r] + bb;
    }
  }
}

// ---------------------------------------------------------------------------
extern "C" void kernel_launch(void* const* d_in, const int* in_sizes, int n_in,
                              void* d_out, int out_size, void* d_ws,
                              size_t ws_size, hipStream_t stream) {
  const float* x = (const float*)d_in[0];
  const float* Wq = (const float*)d_in[1];
  const float* bq = (const float*)d_in[2];
  const float* Wk = (const float*)d_in[3];
  const float* bk = (const float*)d_in[4];
  const float* Wv = (const float*)d_in[5];
  const float* bv = (const float*)d_in[6];
  const float* Wo = (const float*)d_in[7];
  const float* bo = (const float*)d_in[8];
  const float* w1 = (const float*)d_in[9];
  const float* b1 = (const float*)d_in[10];
  const float* w2 = (const float*)d_in[11];
  const float* b2 = (const float*)d_in[12];
  const float* tau = (const float*)d_in[13];
  float* out = (float*)d_out;

  const size_t NX = (size_t)2048 * EE;           // 1M elems (x, o)
  const size_t NW = (size_t)4 * EE * EE;         // 1M elems (4 W's)
  const size_t NQK = (size_t)BB * NH * SS * HD;  // 1M elems
  const size_t NS = (size_t)BB * NH * SS * SS;   // 8.39M elems

  _Float16* xh = (_Float16*)d_ws;
  _Float16* xl = xh + NX;
  _Float16* Wth = xl + NX;
  _Float16* Wtl = Wth + NW;
  _Float16* qh = Wtl + NW;
  _Float16* ql = qh + NQK;
  _Float16* kh = ql + NQK;
  _Float16* kl = kh + NQK;
  _Float16* vth = kl + NQK;
  _Float16* vtl = vth + NQK;
  float* s = (float*)(vtl + NQK);
  float* ma = s + NS;
  float* t_un = ma + (size_t)BB * SS * SS;
  float* T = t_un + (size_t)BB * SS * SS;
  float* rowred = T + 8192;
  float* cst = rowred + 2048 * 8;
  _Float16* ph = (_Float16*)(cst + 16);
  _Float16* pl = ph + NS;
  _Float16* oh = xh;  // alias: x dead after k_qkv_mfma
  _Float16* ol = xl;

  k_prep<<<785, 256, 0, stream>>>(w1, b1, w2, b2, T, x, xh, xl, Wq, Wk, Wv, Wo,
                                  Wth, Wtl);
  k_qkv_mfma<<<dim3(8, 32, 3), 256, 0, stream>>>(xh, xl, Wth, Wtl, bq, bk, bv,
                                                 qh, ql, kh, kl, vth, vtl);
  k_scores_mfma<<<dim3(8, 8, 32), 256, 0, stream>>>(qh, ql, kh, kl, s);
  k_rowstat<<<2048, 64, 0, stream>>>(s, T, ma, t_un, rowred);
  k_consts<<<4, 256, 0, stream>>>(rowred, cst);
  k_blend<<<16384, 64, 0, stream>>>(s, ma, t_un, cst, tau, ph, pl);
  k_av_mfma<<<dim3(8, 32), 256, 0, stream>>>(ph, pl, vth, vtl, oh, ol);
  k_out_mfma<<<dim3(8, 32), 256, 0, stream>>>(oh, ol, Wth, Wtl, bo, out);
}

// Round 10
// 170.496 us; speedup vs baseline: 1.1835x; 1.0050x over previous
//
#include <hip/hip_runtime.h>
#include <math.h>

// Problem constants (fixed by setup_inputs)
#define BB 4
#define SS 512
#define EE 512
#define NH 8
#define HD 64
#define NC 128
#define NTAB 4096  // table intervals over sa in [-0.4, 0.4]

typedef _Float16 f16x8 __attribute__((ext_vector_type(8)));
typedef float f32x4 __attribute__((ext_vector_type(4)));

struct HL { _Float16 h, l; };

__device__ __forceinline__ float clampf(float v, float lo, float hi) {
  return fminf(fmaxf(v, lo), hi);
}
__device__ __forceinline__ HL split16(float x) {
  HL r;
  r.h = (_Float16)x;
  r.l = (_Float16)(x - (float)r.h);
  return r;
}

__device__ __forceinline__ float waveRedSum(float v) {
#pragma unroll
  for (int o = 32; o; o >>= 1) v += __shfl_xor(v, o);
  return v;
}
__device__ __forceinline__ float waveRedMax(float v) {
#pragma unroll
  for (int o = 32; o; o >>= 1) v = fmaxf(v, __shfl_xor(v, o));
  return v;
}
// blockDim.x == 256 (4 waves) assumed
__device__ __forceinline__ float blockRedSum(float v, float* red) {
  int tid = threadIdx.x;
  v = waveRedSum(v);
  __syncthreads();
  if ((tid & 63) == 0) red[tid >> 6] = v;
  __syncthreads();
  return red[0] + red[1] + red[2] + red[3];
}
__device__ __forceinline__ float blockRedMax(float v, float* red) {
  int tid = threadIdx.x;
  v = waveRedMax(v);
  __syncthreads();
  if ((tid & 63) == 0) red[tid >> 6] = v;
  __syncthreads();
  return fmaxf(fmaxf(red[0], red[1]), fmaxf(red[2], red[3]));
}

// ---------------------------------------------------------------------------
// K_prep: fused preprocessing (all independent):
//   blocks [0,17): sigmoid table
//   blocks [17,529): split x -> f16 hi/lo
//   blocks [529,785): transpose+split the 4 weight matrices
__global__ __launch_bounds__(256) void k_prep(
    const float* __restrict__ w1, const float* __restrict__ b1,
    const float* __restrict__ w2, const float* __restrict__ b2,
    float* __restrict__ T, const float* __restrict__ x,
    _Float16* __restrict__ xh, _Float16* __restrict__ xl,
    const float* __restrict__ Wq, const float* __restrict__ Wk,
    const float* __restrict__ Wv, const float* __restrict__ Wo,
    _Float16* __restrict__ Wth, _Float16* __restrict__ Wtl) {
  const int bid = blockIdx.x;
  const int tid = threadIdx.x;
  if (bid < 17) {
    int idx = bid * 256 + tid;
    if (idx > NTAB) return;
    float sa = -0.4f + (float)idx * (0.8f / (float)NTAB);
    float ap = 0.f;
#pragma unroll 4
    for (int c = 0; c < NC; ++c) {
      float h = fminf(fmaxf(sa * w1[c] + b1[c], 0.f), 5.f);
      ap += h * w2[c];
    }
    ap = clampf(ap + b2[0], -5.f, 5.f);
    float tay = clampf(1.0f + 0.05f * (ap * 50.0f), 0.5f, 1.5f);
    T[idx] = 1.0f / (1.0f + expf(-tay));
  } else if (bid < 529) {
    int idx = ((bid - 17) * 256 + tid) * 8;
    float4 u0 = *(const float4*)(x + idx);
    float4 u1 = *(const float4*)(x + idx + 4);
    float f[8] = {u0.x, u0.y, u0.z, u0.w, u1.x, u1.y, u1.z, u1.w};
    f16x8 h, l;
#pragma unroll
    for (int j = 0; j < 8; ++j) {
      HL r = split16(f[j]);
      h[j] = r.h;
      l[j] = r.l;
    }
    *(f16x8*)(xh + idx) = h;
    *(f16x8*)(xl + idx) = l;
  } else {
    const int j = bid - 529;          // [0,256)
    const int z = j >> 6;             // matrix
    const int rem = j & 63;
    const int k0 = (rem & 7) * 64, n0 = (rem >> 3) * 64;
    const float* W = (z == 0) ? Wq : (z == 1) ? Wk : (z == 2) ? Wv : Wo;
    __shared__ float Tt[64][68];
    const int r = tid >> 2, c = (tid & 3) * 16;
#pragma unroll
    for (int jj = 0; jj < 16; jj += 4)
      *(float4*)&Tt[r][c + jj] =
          *(const float4*)(W + (size_t)(k0 + r) * EE + n0 + c + jj);
    __syncthreads();
    f16x8 h0, l0, h1, l1;
#pragma unroll
    for (int jj = 0; jj < 8; ++jj) {
      HL r0 = split16(Tt[c + jj][r]);
      HL r1 = split16(Tt[c + 8 + jj][r]);
      h0[jj] = r0.h; l0[jj] = r0.l;
      h1[jj] = r1.h; l1[jj] = r1.l;
    }
    _Float16* dh = Wth + ((size_t)z * EE + n0 + r) * EE + k0 + c;
    _Float16* dl = Wtl + ((size_t)z * EE + n0 + r) * EE + k0 + c;
    *(f16x8*)dh = h0;
    *(f16x8*)(dh + 8) = h1;
    *(f16x8*)dl = l0;
    *(f16x8*)(dl + 8) = l1;
  }
}

// ---------------------------------------------------------------------------
// K_qkv: LDS-staged 3-term f16 MFMA GEMM. Block = 64m x 64n, 4 waves stacked
// in m. q is pre-scaled by 0.125. For which==2 (V), the output tile (one head,
// 64si x 64d) is transposed in LDS and written directly as v_t hi/lo
// [bh][d][si].
__global__ __launch_bounds__(256) void k_qkv_mfma(
    const _Float16* __restrict__ xh, const _Float16* __restrict__ xl,
    const _Float16* __restrict__ Wth, const _Float16* __restrict__ Wtl,
    const float* __restrict__ bq, const float* __restrict__ bk,
    const float* __restrict__ bv,
    _Float16* __restrict__ qh, _Float16* __restrict__ ql,
    _Float16* __restrict__ kh, _Float16* __restrict__ kl,
    _Float16* __restrict__ vth, _Float16* __restrict__ vtl) {
  const int which = blockIdx.z;
  const int tid = threadIdx.x;
  const int wave = tid >> 6, lane = tid & 63;
  const int quad = lane >> 4, l16 = lane & 15;
  const int m0 = blockIdx.y * 64;
  const int n0 = blockIdx.x * 64;
  const _Float16* Bh = Wth + (size_t)which * EE * EE;
  const _Float16* Bl = Wtl + (size_t)which * EE * EE;

  __shared__ __align__(16) char smpool[36864];
  _Float16(*LAh)[72] = (_Float16(*)[72])(smpool);
  _Float16(*LAl)[72] = (_Float16(*)[72])(smpool + 9216);
  _Float16(*LBh)[72] = (_Float16(*)[72])(smpool + 18432);
  _Float16(*LBl)[72] = (_Float16(*)[72])(smpool + 27648);
  float(*TR)[68] = (float(*)[68])(smpool);  // reused for V transpose

  const int sr0 = tid >> 3, sc0 = (tid & 7) * 8;
  const int sr1 = (tid + 256) >> 3, sc1 = sc0;

  f32x4 acc[4] = {};
  for (int k0 = 0; k0 < EE; k0 += 64) {
    if (k0) __syncthreads();
    *(f16x8*)&LAh[sr0][sc0] = *(const f16x8*)(xh + (size_t)(m0 + sr0) * EE + k0 + sc0);
    *(f16x8*)&LAl[sr0][sc0] = *(const f16x8*)(xl + (size_t)(m0 + sr0) * EE + k0 + sc0);
    *(f16x8*)&LBh[sr0][sc0] = *(const f16x8*)(Bh + (size_t)(n0 + sr0) * EE + k0 + sc0);
    *(f16x8*)&LBl[sr0][sc0] = *(const f16x8*)(Bl + (size_t)(n0 + sr0) * EE + k0 + sc0);
    *(f16x8*)&LAh[sr1][sc1] = *(const f16x8*)(xh + (size_t)(m0 + sr1) * EE + k0 + sc1);
    *(f16x8*)&LAl[sr1][sc1] = *(const f16x8*)(xl + (size_t)(m0 + sr1) * EE + k0 + sc1);
    *(f16x8*)&LBh[sr1][sc1] = *(const f16x8*)(Bh + (size_t)(n0 + sr1) * EE + k0 + sc1);
    *(f16x8*)&LBl[sr1][sc1] = *(const f16x8*)(Bl + (size_t)(n0 + sr1) * EE + k0 + sc1);
    __syncthreads();
#pragma unroll
    for (int kk = 0; kk < 64; kk += 32) {
      f16x8 ah = *(const f16x8*)&LAh[wave * 16 + l16][kk + quad * 8];
      f16x8 al = *(const f16x8*)&LAl[wave * 16 + l16][kk + quad * 8];
#pragma unroll
      for (int nt = 0; nt < 4; ++nt) {
        f16x8 bhf = *(const f16x8*)&LBh[nt * 16 + l16][kk + quad * 8];
        f16x8 blf = *(const f16x8*)&LBl[nt * 16 + l16][kk + quad * 8];
        acc[nt] = __builtin_amdgcn_mfma_f32_16x16x32_f16(ah, bhf, acc[nt], 0, 0, 0);
        acc[nt] = __builtin_amdgcn_mfma_f32_16x16x32_f16(ah, blf, acc[nt], 0, 0, 0);
        acc[nt] = __builtin_amdgcn_mfma_f32_16x16x32_f16(al, bhf, acc[nt], 0, 0, 0);
      }
    }
  }
  const float* bias = (which == 0) ? bq : (which == 1) ? bk : bv;
  if (which == 2) {
    // V path: bias-add, transpose via LDS, store split-f16 [bh][d][si]
    __syncthreads();  // main-loop LDS reads done before overwrite
#pragma unroll
    for (int nt = 0; nt < 4; ++nt) {
      const int dcol = nt * 16 + l16;             // d within head
      const float bb = bias[n0 + nt * 16 + l16];  // n0 = head*64
#pragma unroll
      for (int r = 0; r < 4; ++r)
        TR[dcol][wave * 16 + quad * 4 + r] = acc[nt][r] + bb;
    }
    __syncthreads();
    const int d = tid >> 2, cc = (tid & 3) * 16;
    const int bh = (m0 >> 9) * NH + (n0 >> 6);
    const int si0 = m0 & 511;
    f16x8 h0, l0, h1, l1;
#pragma unroll
    for (int jj = 0; jj < 8; ++jj) {
      HL r0 = split16(TR[d][cc + jj]);
      HL r1 = split16(TR[d][cc + 8 + jj]);
      h0[jj] = r0.h; l0[jj] = r0.l;
      h1[jj] = r1.h; l1[jj] = r1.l;
    }
    _Float16* dh = vth + ((size_t)bh * HD + d) * SS + si0 + cc;
    _Float16* dl = vtl + ((size_t)bh * HD + d) * SS + si0 + cc;
    *(f16x8*)dh = h0;
    *(f16x8*)(dh + 8) = h1;
    *(f16x8*)dl = l0;
    *(f16x8*)(dl + 8) = l1;
  } else {
    const float postscale = (which == 0) ? 0.125f : 1.0f;
    const int mbase = m0 + wave * 16 + quad * 4;
#pragma unroll
    for (int nt = 0; nt < 4; ++nt) {
      const int col = n0 + nt * 16 + l16;
      const float bb = bias[col];
      const int hh = col >> 6, d = col & 63;
#pragma unroll
      for (int r = 0; r < 4; ++r) {
        const int mm = mbase + r;
        const int b_ = mm >> 9, si = mm & 511;
        const size_t idx = (((size_t)(b_ * NH + hh)) * SS + si) * HD + d;
        const float val = (acc[nt][r] + bb) * postscale;
        HL sp = split16(val);
        (which ? kh : qh)[idx] = sp.h;
        (which ? kl : ql)[idx] = sp.l;
      }
    }
  }
}

// ---------------------------------------------------------------------------
// K_scores: s = clip(q.k^T, -15, 15) via 3-term f16 MFMA (q pre-scaled).
// LDS-staged: Q and K 64-row tiles staged once per block, then pure
// ds_read+MFMA. grid (8 jT, 8 iT, 32 bh), block 256 (4 waves stacked in m).
__global__ __launch_bounds__(256) void k_scores_mfma(
    const _Float16* __restrict__ qh, const _Float16* __restrict__ ql,
    const _Float16* __restrict__ kh, const _Float16* __restrict__ kl,
    float* __restrict__ s) {
  const int bh = blockIdx.z;
  const int i0 = blockIdx.y * 64, j0 = blockIdx.x * 64;
  const int tid = threadIdx.x;
  const int wave = tid >> 6, lane = tid & 63;
  const int quad = lane >> 4, l16 = lane & 15;

  __shared__ _Float16 Qh[64][72], Ql[64][72], Kh[64][72], Kl[64][72];
  // stage: thread t -> row r = t>>2, cols c..c+15 (two f16x8 per array)
  const int r = tid >> 2, c = (tid & 3) * 16;
  {
    const size_t qoff = ((size_t)bh * SS + i0 + r) * HD + c;
    const size_t koff = ((size_t)bh * SS + j0 + r) * HD + c;
    *(f16x8*)&Qh[r][c] = *(const f16x8*)(qh + qoff);
    *(f16x8*)&Qh[r][c + 8] = *(const f16x8*)(qh + qoff + 8);
    *(f16x8*)&Ql[r][c] = *(const f16x8*)(ql + qoff);
    *(f16x8*)&Ql[r][c + 8] = *(const f16x8*)(ql + qoff + 8);
    *(f16x8*)&Kh[r][c] = *(const f16x8*)(kh + koff);
    *(f16x8*)&Kh[r][c + 8] = *(const f16x8*)(kh + koff + 8);
    *(f16x8*)&Kl[r][c] = *(const f16x8*)(kl + koff);
    *(f16x8*)&Kl[r][c + 8] = *(const f16x8*)(kl + koff + 8);
  }
  __syncthreads();

  f16x8 a_hi[2], a_lo[2];
#pragma unroll
  for (int ks = 0; ks < 2; ++ks) {
    a_hi[ks] = *(const f16x8*)&Qh[wave * 16 + l16][ks * 32 + quad * 8];
    a_lo[ks] = *(const f16x8*)&Ql[wave * 16 + l16][ks * 32 + quad * 8];
  }
  f32x4 acc[4] = {};
#pragma unroll
  for (int ks = 0; ks < 2; ++ks) {
#pragma unroll
    for (int t = 0; t < 4; ++t) {
      f16x8 b_hi = *(const f16x8*)&Kh[t * 16 + l16][ks * 32 + quad * 8];
      f16x8 b_lo = *(const f16x8*)&Kl[t * 16 + l16][ks * 32 + quad * 8];
      acc[t] = __builtin_amdgcn_mfma_f32_16x16x32_f16(a_hi[ks], b_hi,
                                                      acc[t], 0, 0, 0);
      acc[t] = __builtin_amdgcn_mfma_f32_16x16x32_f16(a_hi[ks], b_lo,
                                                      acc[t], 0, 0, 0);
      acc[t] = __builtin_amdgcn_mfma_f32_16x16x32_f16(a_lo[ks], b_hi,
                                                      acc[t], 0, 0, 0);
    }
  }
  float* sb = s + (size_t)bh * SS * SS;
#pragma unroll
  for (int t = 0; t < 4; ++t) {
#pragma unroll
    for (int r2 = 0; r2 < 4; ++r2) {
      float val = clampf(acc[t][r2], -15.0f, 15.0f);  // inputs finite
      sb[(size_t)(i0 + wave * 16 + quad * 4 + r2) * SS + j0 + t * 16 + l16] = val;
    }
  }
}

// ---------------------------------------------------------------------------
// K_rowstat: per-row fused ma + autopoietic transform (one wave per row).
__global__ __launch_bounds__(64) void k_rowstat(
    const float* __restrict__ s, const float* __restrict__ T,
    float* __restrict__ ma, float* __restrict__ t_un,
    float* __restrict__ rowred) {
  const int row = blockIdx.x;  // b*S + i
  const int b_ = row >> 9, i = row & 511;
  const int lane = threadIdx.x;

  float4 a0 = {0.f, 0.f, 0.f, 0.f}, a1 = {0.f, 0.f, 0.f, 0.f};
#pragma unroll
  for (int hh = 0; hh < NH; ++hh) {
    const float4* p = reinterpret_cast<const float4*>(
                          s + (((size_t)(b_ * NH + hh) * SS) + i) * SS) +
                      lane * 2;
    float4 u0 = p[0], u1 = p[1];
    a0.x += u0.x; a0.y += u0.y; a0.z += u0.z; a0.w += u0.w;
    a1.x += u1.x; a1.y += u1.y; a1.z += u1.z; a1.w += u1.w;
  }
  float m[8] = {a0.x * 0.125f, a0.y * 0.125f, a0.z * 0.125f, a0.w * 0.125f,
                a1.x * 0.125f, a1.y * 0.125f, a1.z * 0.125f, a1.w * 0.125f};
  {
    float4* mp = reinterpret_cast<float4*>(ma + ((size_t)b_ * SS + i) * SS) +
                 lane * 2;
    float4 w0 = {m[0], m[1], m[2], m[3]}, w1v = {m[4], m[5], m[6], m[7]};
    mp[0] = w0;
    mp[1] = w1v;
  }
  float sma = 0.f, sma2 = 0.f, mabs = 0.f;
#pragma unroll
  for (int e = 0; e < 8; ++e) {
    sma += m[e];
    sma2 += m[e] * m[e];
    mabs = fmaxf(mabs, fabsf(m[e]));
  }
  sma = waveRedSum(sma);
  sma2 = waveRedSum(sma2);
  mabs = waveRedMax(mabs);

  float ex[8], esum = 0.f;
#pragma unroll
  for (int e = 0; e < 8; ++e) {
    ex[e] = expf(clampf(m[e], -10.f, 10.f));
    esum += ex[e];
  }
  esum = waveRedSum(esum);
  float inv = 1.0f / esum;
  float Hv[8], sH = 0.f;
#pragma unroll
  for (int e = 0; e < 8; ++e) {
    float p = ex[e] * inv;
    Hv[e] = -p * logf(p + 1e-6f);
    sH += Hv[e];
  }
  sH = waveRedSum(sH);

  float fx[8], fsum = 0.f;
#pragma unroll
  for (int e = 0; e < 8; ++e) {
    fx[e] = expf(3.0f * Hv[e]);
    fsum += fx[e];
  }
  fsum = waveRedSum(fsum);
  float finv = 1.0f / fsum;

  float t[8], st = 0.f, st2 = 0.f;
#pragma unroll
  for (int e = 0; e < 8; ++e) {
    float sa = clampf(m[e], -8.f, 8.f) * 0.05f;
    float pos = (sa + 0.4f) * ((float)NTAB / 0.8f);
    int idx = (int)pos;
    idx = idx < 0 ? 0 : (idx > NTAB - 1 ? NTAB - 1 : idx);
    float frac = pos - (float)idx;
    float g0 = T[idx], g1 = T[idx + 1];
    float sig = g0 + (g1 - g0) * frac;
    t[e] = sig * fx[e] * finv;
    st += t[e];
    st2 += t[e] * t[e];
  }
  st = waveRedSum(st);
  st2 = waveRedSum(st2);
  {
    float4* tp = reinterpret_cast<float4*>(t_un + ((size_t)b_ * SS + i) * SS) +
                 lane * 2;
    float4 w0 = {t[0], t[1], t[2], t[3]}, w1v = {t[4], t[5], t[6], t[7]};
    tp[0] = w0;
    tp[1] = w1v;
  }
  if (lane == 0) {
    float* rp = rowred + (size_t)row * 8;
    rp[0] = sma; rp[1] = sma2; rp[2] = mabs;
    rp[3] = st;  rp[4] = st2;  rp[5] = sH;
  }
}

// ---------------------------------------------------------------------------
// K_consts: reduce per-row partials -> per-batch blend constants.
__global__ __launch_bounds__(256) void k_consts(
    const float* __restrict__ rowred, float* __restrict__ cst) {
  const int b_ = blockIdx.x;
  const int tid = threadIdx.x;
  __shared__ float red[4];
  const float* r0 = rowred + ((size_t)b_ * SS + tid * 2) * 8;
  const float* r1 = r0 + 8;
  float sma = blockRedSum(r0[0] + r1[0], red);
  float sma2 = blockRedSum(r0[1] + r1[1], red);
  float mabs = blockRedMax(fmaxf(r0[2], r1[2]), red);
  float st = blockRedSum(r0[3] + r1[3], red);
  float st2 = blockRedSum(r0[4] + r1[4], red);
  float sH = blockRedSum(r0[5] + r1[5], red);
  if (tid == 0) {
    const float N = (float)(SS * SS);
    float eo = sqrtf(sma2) + 1e-4f;
    float et = sqrtf(st2) + 1e-4f;
    float r = clampf(eo / et, 0.8f, 1.2f);
    float tmean = r * st / N;
    float om = sma / N;
    float vart = r * r * fmaxf(st2 / N - (st / N) * (st / N), 0.f);
    float tstd = sqrtf(fmaxf(vart, 0.01f));
    float varo = fmaxf(sma2 / N - om * om, 0.f);
    float ostd = sqrtf(fmaxf(varo, 0.01f));
    float gd = clampf(ostd / tstd, 0.8f, 1.2f);
    float ar = clampf(mabs, 1.f, 10.f);
    float sm = clampf(0.3f / log1pf(ar), 0.1f, 0.5f);
    float ent = sH / N;
    float ne = ent / logf((float)SS);
    float rr = 0.4f * (1.f - clampf(ne, 0.f, 0.4f));
    float G = sm * gd;
    cst[b_ * 4 + 0] = rr * (1.f - G) * tmean;  // c0
    cst[b_ * 4 + 1] = rr * G * r;              // c1 (multiplies t_un)
    cst[b_ * 4 + 2] = rr;                      // c2 (multiplies ma)
  }
}

// ---------------------------------------------------------------------------
// K_av_fused: out = softmax(blend(s)) @ v with NO materialized p.
// Normalization is linear: out = (sum_j e_ij v_j) / Z_i, so the LDS-stage
// threads compute UNNORMALIZED e' = exp(blend)*2^-16 (f16-safe: |vv|<=~19.5
// -> e' <= ~4.4e3 < 65504), split to f16 hi/lo into LDS, and accumulate
// per-row Z partials in fp32. Waves run the pure ds_read+MFMA loop; epilogue
// divides by Z (the 2^-16 cancels). Block = 64m x full head. grid (8 mb,32 bh).
__global__ __launch_bounds__(256) void k_av_fused(
    const float* __restrict__ s, const float* __restrict__ ma,
    const float* __restrict__ t_un, const float* __restrict__ cst,
    const float* __restrict__ tau, const _Float16* __restrict__ vth,
    const _Float16* __restrict__ vtl, _Float16* __restrict__ oh,
    _Float16* __restrict__ ol) {
  const int bh = blockIdx.y;
  const int b_ = bh >> 3, hh = bh & 7;
  const int m0 = blockIdx.x * 64;
  const int tid = threadIdx.x;
  const int wave = tid >> 6, lane = tid & 63;
  const int quad = lane >> 4, l16 = lane & 15;

  const float c0 = cst[b_ * 4 + 0], c1 = cst[b_ * 4 + 1], c2 = cst[b_ * 4 + 2];
  const float itau = 1.0f / tau[0];

  __shared__ _Float16 Ph[64][40], Pl[64][40];
  __shared__ float Zp[64][4];

  const int srow = tid >> 2;          // stage row 0..63 (fixed per thread)
  const int ci = tid & 3;             // chunk index 0..3
  const int schunk = ci * 8;
  const size_t sbase = ((size_t)bh * SS + m0 + srow) * SS + schunk;
  const size_t mbase = ((size_t)b_ * SS + m0 + srow) * SS + schunk;

  // register-prefetch k0=0
  float4 sv0 = *(const float4*)(s + sbase);
  float4 sv1 = *(const float4*)(s + sbase + 4);
  float4 mv0 = *(const float4*)(ma + mbase);
  float4 mv1 = *(const float4*)(ma + mbase + 4);
  float4 tv0 = *(const float4*)(t_un + mbase);
  float4 tv1 = *(const float4*)(t_un + mbase + 4);

  float zpart = 0.f;
  f32x4 acc[4] = {};
  for (int k0 = 0; k0 < SS; k0 += 32) {
    if (k0) __syncthreads();  // prior-stage LDS reads done
    {
      float svv[8] = {sv0.x, sv0.y, sv0.z, sv0.w, sv1.x, sv1.y, sv1.z, sv1.w};
      float mvv[8] = {mv0.x, mv0.y, mv0.z, mv0.w, mv1.x, mv1.y, mv1.z, mv1.w};
      float tvv[8] = {tv0.x, tv0.y, tv0.z, tv0.w, tv1.x, tv1.y, tv1.z, tv1.w};
      f16x8 hv, lv;
#pragma unroll
      for (int j = 0; j < 8; ++j) {
        float vv = (svv[j] + c0 + c1 * tvv[j] - c2 * mvv[j]) * itau;
        float e = expf(vv) * 1.52587890625e-05f;  // * 2^-16
        zpart += e;
        HL r = split16(e);
        hv[j] = r.h;
        lv[j] = r.l;
      }
      *(f16x8*)&Ph[srow][schunk] = hv;
      *(f16x8*)&Pl[srow][schunk] = lv;
    }
    __syncthreads();
    if (k0 + 32 < SS) {
      sv0 = *(const float4*)(s + sbase + k0 + 32);
      sv1 = *(const float4*)(s + sbase + k0 + 36);
      mv0 = *(const float4*)(ma + mbase + k0 + 32);
      mv1 = *(const float4*)(ma + mbase + k0 + 36);
      tv0 = *(const float4*)(t_un + mbase + k0 + 32);
      tv1 = *(const float4*)(t_un + mbase + k0 + 36);
    }
    const size_t boff = ((size_t)bh * HD + wave * 16 + l16) * SS + k0 + quad * 8;
    f16x8 bh_ = *(const f16x8*)(vth + boff);
    f16x8 bl_ = *(const f16x8*)(vtl + boff);
#pragma unroll
    for (int mt = 0; mt < 4; ++mt) {
      f16x8 ah = *(const f16x8*)&Ph[mt * 16 + l16][quad * 8];
      f16x8 al = *(const f16x8*)&Pl[mt * 16 + l16][quad * 8];
      acc[mt] = __builtin_amdgcn_mfma_f32_16x16x32_f16(ah, bh_, acc[mt], 0, 0, 0);
      acc[mt] = __builtin_amdgcn_mfma_f32_16x16x32_f16(ah, bl_, acc[mt], 0, 0, 0);
      acc[mt] = __builtin_amdgcn_mfma_f32_16x16x32_f16(al, bh_, acc[mt], 0, 0, 0);
    }
  }
  __syncthreads();
  Zp[srow][ci] = zpart;
  __syncthreads();
#pragma unroll
  for (int mt = 0; mt < 4; ++mt) {
#pragma unroll
    for (int r = 0; r < 4; ++r) {
      const int lr = mt * 16 + quad * 4 + r;  // local row
      const float Z = Zp[lr][0] + Zp[lr][1] + Zp[lr][2] + Zp[lr][3];
      const float oV = acc[mt][r] / Z;
      const int si = m0 + lr;
      const size_t idx =
          ((size_t)(b_ * SS + si)) * EE + hh * HD + wave * 16 + l16;
      HL sp = split16(oV);
      oh[idx] = sp.h;
      ol[idx] = sp.l;
    }
  }
}

// ---------------------------------------------------------------------------
// K_out: LDS-staged 3-term f16 MFMA GEMM, fp32 output + bias.
// Same structure as k_qkv_mfma. grid (8 nb, 32 mb), block 256.
__global__ __launch_bounds__(256) void k_out_mfma(
    const _Float16* __restrict__ oh, const _Float16* __restrict__ ol,
    const _Float16* __restrict__ Wth, const _Float16* __restrict__ Wtl,
    const float* __restrict__ bo, float* __restrict__ out) {
  const int tid = threadIdx.x;
  const int wave = tid >> 6, lane = tid & 63;
  const int quad = lane >> 4, l16 = lane & 15;
  const int m0 = blockIdx.y * 64;
  const int n0 = blockIdx.x * 64;
  const _Float16* Bh = Wth + (size_t)3 * EE * EE;  // Wo^T
  const _Float16* Bl = Wtl + (size_t)3 * EE * EE;

  __shared__ _Float16 LAh[64][72], LAl[64][72], LBh[64][72], LBl[64][72];

  const int sr0 = tid >> 3, sc0 = (tid & 7) * 8;
  const int sr1 = (tid + 256) >> 3, sc1 = sc0;

  f32x4 acc[4] = {};
  for (int k0 = 0; k0 < EE; k0 += 64) {
    if (k0) __syncthreads();
    *(f16x8*)&LAh[sr0][sc0] = *(const f16x8*)(oh + (size_t)(m0 + sr0) * EE + k0 + sc0);
    *(f16x8*)&LAl[sr0][sc0] = *(const f16x8*)(ol + (size_t)(m0 + sr0) * EE + k0 + sc0);
    *(f16x8*)&LBh[sr0][sc0] = *(const f16x8*)(Bh + (size_t)(n0 + sr0) * EE + k0 + sc0);
    *(f16x8*)&LBl[sr0][sc0] = *(const f16x8*)(Bl + (size_t)(n0 + sr0) * EE + k0 + sc0);
    *(f16x8*)&LAh[sr1][sc1] = *(const f16x8*)(oh + (size_t)(m0 + sr1) * EE + k0 + sc1);
    *(f16x8*)&LAl[sr1][sc1] = *(const f16x8*)(ol + (size_t)(m0 + sr1) * EE + k0 + sc1);
    *(f16x8*)&LBh[sr1][sc1] = *(const f16x8*)(Bh + (size_t)(n0 + sr1) * EE + k0 + sc1);
    *(f16x8*)&LBl[sr1][sc1] = *(const f16x8*)(Bl + (size_t)(n0 + sr1) * EE + k0 + sc1);
    __syncthreads();
#pragma unroll
    for (int kk = 0; kk < 64; kk += 32) {
      f16x8 ah = *(const f16x8*)&LAh[wave * 16 + l16][kk + quad * 8];
      f16x8 al = *(const f16x8*)&LAl[wave * 16 + l16][kk + quad * 8];
#pragma unroll
      for (int nt = 0; nt < 4; ++nt) {
        f16x8 bhf = *(const f16x8*)&LBh[nt * 16 + l16][kk + quad * 8];
        f16x8 blf = *(const f16x8*)&LBl[nt * 16 + l16][kk + quad * 8];
        acc[nt] = __builtin_amdgcn_mfma_f32_16x16x32_f16(ah, bhf, acc[nt], 0, 0, 0);
        acc[nt] = __builtin_amdgcn_mfma_f32_16x16x32_f16(ah, blf, acc[nt], 0, 0, 0);
        acc[nt] = __builtin_amdgcn_mfma_f32_16x16x32_f16(al, bhf, acc[nt], 0, 0, 0);
      }
    }
  }
  const int mbase = m0 + wave * 16 + quad * 4;
#pragma unroll
  for (int nt = 0; nt < 4; ++nt) {
    const int col = n0 + nt * 16 + l16;
    const float bb = bo[col];
#pragma unroll
    for (int r = 0; r < 4; ++r) {
      const int m = mbase + r;
      out[(size_t)m * EE + col] = acc[nt][r] + bb;
    }
  }
}

// ---------------------------------------------------------------------------
extern "C" void kernel_launch(void* const* d_in, const int* in_sizes, int n_in,
                              void* d_out, int out_size, void* d_ws,
                              size_t ws_size, hipStream_t stream) {
  const float* x = (const float*)d_in[0];
  const float* Wq = (const float*)d_in[1];
  const float* bq = (const float*)d_in[2];
  const float* Wk = (const float*)d_in[3];
  const float* bk = (const float*)d_in[4];
  const float* Wv = (const float*)d_in[5];
  const float* bv = (const float*)d_in[6];
  const float* Wo = (const float*)d_in[7];
  const float* bo = (const float*)d_in[8];
  const float* w1 = (const float*)d_in[9];
  const float* b1 = (const float*)d_in[10];
  const float* w2 = (const float*)d_in[11];
  const float* b2 = (const float*)d_in[12];
  const float* tau = (const float*)d_in[13];
  float* out = (float*)d_out;

  const size_t NX = (size_t)2048 * EE;           // 1M elems (x, o)
  const size_t NW = (size_t)4 * EE * EE;         // 1M elems (4 W's)
  const size_t NQK = (size_t)BB * NH * SS * HD;  // 1M elems
  const size_t NS = (size_t)BB * NH * SS * SS;   // 8.39M elems

  _Float16* xh = (_Float16*)d_ws;
  _Float16* xl = xh + NX;
  _Float16* Wth = xl + NX;
  _Float16* Wtl = Wth + NW;
  _Float16* qh = Wtl + NW;
  _Float16* ql = qh + NQK;
  _Float16* kh = ql + NQK;
  _Float16* kl = kh + NQK;
  _Float16* vth = kl + NQK;
  _Float16* vtl = vth + NQK;
  float* s = (float*)(vtl + NQK);
  float* ma = s + NS;
  float* t_un = ma + (size_t)BB * SS * SS;
  float* T = t_un + (size_t)BB * SS * SS;
  float* rowred = T + 8192;
  float* cst = rowred + 2048 * 8;
  _Float16* oh = xh;  // alias: x dead after k_qkv_mfma
  _Float16* ol = xl;

  k_prep<<<785, 256, 0, stream>>>(w1, b1, w2, b2, T, x, xh, xl, Wq, Wk, Wv, Wo,
                                  Wth, Wtl);
  k_qkv_mfma<<<dim3(8, 32, 3), 256, 0, stream>>>(xh, xl, Wth, Wtl, bq, bk, bv,
                                                 qh, ql, kh, kl, vth, vtl);
  k_scores_mfma<<<dim3(8, 8, 32), 256, 0, stream>>>(qh, ql, kh, kl, s);
  k_rowstat<<<2048, 64, 0, stream>>>(s, T, ma, t_un, rowred);
  k_consts<<<4, 256, 0, stream>>>(rowred, cst);
  k_av_fused<<<dim3(8, 32), 256, 0, stream>>>(s, ma, t_un, cst, tau, vth, vtl,
                                              oh, ol);
  k_out_mfma<<<dim3(8, 32), 256, 0, stream>>>(oh, ol, Wth, Wtl, bo, out);
}

// Round 11
// 167.432 us; speedup vs baseline: 1.2052x; 1.0183x over previous
//
#include <hip/hip_runtime.h>
#include <math.h>

// Problem constants (fixed by setup_inputs)
#define BB 4
#define SS 512
#define EE 512
#define NH 8
#define HD 64
#define NC 128
#define NTAB 4096  // table intervals over sa in [-0.4, 0.4]

typedef _Float16 f16x8 __attribute__((ext_vector_type(8)));
typedef float f32x4 __attribute__((ext_vector_type(4)));

struct HL { _Float16 h, l; };

__device__ __forceinline__ float clampf(float v, float lo, float hi) {
  return fminf(fmaxf(v, lo), hi);
}
__device__ __forceinline__ HL split16(float x) {
  HL r;
  r.h = (_Float16)x;
  r.l = (_Float16)(x - (float)r.h);
  return r;
}

__device__ __forceinline__ float waveRedSum(float v) {
#pragma unroll
  for (int o = 32; o; o >>= 1) v += __shfl_xor(v, o);
  return v;
}
__device__ __forceinline__ float waveRedMax(float v) {
#pragma unroll
  for (int o = 32; o; o >>= 1) v = fmaxf(v, __shfl_xor(v, o));
  return v;
}
// blockDim.x == 256 (4 waves) assumed
__device__ __forceinline__ float blockRedSum(float v, float* red) {
  int tid = threadIdx.x;
  v = waveRedSum(v);
  __syncthreads();
  if ((tid & 63) == 0) red[tid >> 6] = v;
  __syncthreads();
  return red[0] + red[1] + red[2] + red[3];
}
__device__ __forceinline__ float blockRedMax(float v, float* red) {
  int tid = threadIdx.x;
  v = waveRedMax(v);
  __syncthreads();
  if ((tid & 63) == 0) red[tid >> 6] = v;
  __syncthreads();
  return fmaxf(fmaxf(red[0], red[1]), fmaxf(red[2], red[3]));
}

// ---------------------------------------------------------------------------
// K_prep: fused preprocessing (all independent):
//   blocks [0,17): sigmoid table
//   blocks [17,529): split x -> f16 hi/lo
//   blocks [529,785): transpose+split the 4 weight matrices
__global__ __launch_bounds__(256) void k_prep(
    const float* __restrict__ w1, const float* __restrict__ b1,
    const float* __restrict__ w2, const float* __restrict__ b2,
    float* __restrict__ T, const float* __restrict__ x,
    _Float16* __restrict__ xh, _Float16* __restrict__ xl,
    const float* __restrict__ Wq, const float* __restrict__ Wk,
    const float* __restrict__ Wv, const float* __restrict__ Wo,
    _Float16* __restrict__ Wth, _Float16* __restrict__ Wtl) {
  const int bid = blockIdx.x;
  const int tid = threadIdx.x;
  if (bid < 17) {
    int idx = bid * 256 + tid;
    if (idx > NTAB) return;
    float sa = -0.4f + (float)idx * (0.8f / (float)NTAB);
    float ap = 0.f;
#pragma unroll 4
    for (int c = 0; c < NC; ++c) {
      float h = fminf(fmaxf(sa * w1[c] + b1[c], 0.f), 5.f);
      ap += h * w2[c];
    }
    ap = clampf(ap + b2[0], -5.f, 5.f);
    float tay = clampf(1.0f + 0.05f * (ap * 50.0f), 0.5f, 1.5f);
    T[idx] = 1.0f / (1.0f + expf(-tay));
  } else if (bid < 529) {
    int idx = ((bid - 17) * 256 + tid) * 8;
    float4 u0 = *(const float4*)(x + idx);
    float4 u1 = *(const float4*)(x + idx + 4);
    float f[8] = {u0.x, u0.y, u0.z, u0.w, u1.x, u1.y, u1.z, u1.w};
    f16x8 h, l;
#pragma unroll
    for (int j = 0; j < 8; ++j) {
      HL r = split16(f[j]);
      h[j] = r.h;
      l[j] = r.l;
    }
    *(f16x8*)(xh + idx) = h;
    *(f16x8*)(xl + idx) = l;
  } else {
    const int j = bid - 529;          // [0,256)
    const int z = j >> 6;             // matrix
    const int rem = j & 63;
    const int k0 = (rem & 7) * 64, n0 = (rem >> 3) * 64;
    const float* W = (z == 0) ? Wq : (z == 1) ? Wk : (z == 2) ? Wv : Wo;
    __shared__ float Tt[64][68];
    const int r = tid >> 2, c = (tid & 3) * 16;
#pragma unroll
    for (int jj = 0; jj < 16; jj += 4)
      *(float4*)&Tt[r][c + jj] =
          *(const float4*)(W + (size_t)(k0 + r) * EE + n0 + c + jj);
    __syncthreads();
    f16x8 h0, l0, h1, l1;
#pragma unroll
    for (int jj = 0; jj < 8; ++jj) {
      HL r0 = split16(Tt[c + jj][r]);
      HL r1 = split16(Tt[c + 8 + jj][r]);
      h0[jj] = r0.h; l0[jj] = r0.l;
      h1[jj] = r1.h; l1[jj] = r1.l;
    }
    _Float16* dh = Wth + ((size_t)z * EE + n0 + r) * EE + k0 + c;
    _Float16* dl = Wtl + ((size_t)z * EE + n0 + r) * EE + k0 + c;
    *(f16x8*)dh = h0;
    *(f16x8*)(dh + 8) = h1;
    *(f16x8*)dl = l0;
    *(f16x8*)(dl + 8) = l1;
  }
}

// ---------------------------------------------------------------------------
// K_qkv: LDS-staged 3-term f16 MFMA GEMM with REGISTER-PREFETCH pipelining:
// the next K-stage's fragments load into VGPRs while the current stage's
// MFMAs run, hiding the L2/L3 latency. Block = 64m x 64n, 4 waves stacked in
// m. q is pre-scaled by 0.125. which==2 (V): transpose in LDS, store v_t.
__global__ __launch_bounds__(256) void k_qkv_mfma(
    const _Float16* __restrict__ xh, const _Float16* __restrict__ xl,
    const _Float16* __restrict__ Wth, const _Float16* __restrict__ Wtl,
    const float* __restrict__ bq, const float* __restrict__ bk,
    const float* __restrict__ bv,
    _Float16* __restrict__ qh, _Float16* __restrict__ ql,
    _Float16* __restrict__ kh, _Float16* __restrict__ kl,
    _Float16* __restrict__ vth, _Float16* __restrict__ vtl) {
  const int which = blockIdx.z;
  const int tid = threadIdx.x;
  const int wave = tid >> 6, lane = tid & 63;
  const int quad = lane >> 4, l16 = lane & 15;
  const int m0 = blockIdx.y * 64;
  const int n0 = blockIdx.x * 64;
  const _Float16* Bh = Wth + (size_t)which * EE * EE;
  const _Float16* Bl = Wtl + (size_t)which * EE * EE;

  __shared__ __align__(16) char smpool[36864];
  _Float16(*LAh)[72] = (_Float16(*)[72])(smpool);
  _Float16(*LAl)[72] = (_Float16(*)[72])(smpool + 9216);
  _Float16(*LBh)[72] = (_Float16(*)[72])(smpool + 18432);
  _Float16(*LBl)[72] = (_Float16(*)[72])(smpool + 27648);
  float(*TR)[68] = (float(*)[68])(smpool);  // reused for V transpose

  const int sr0 = tid >> 3, sc0 = (tid & 7) * 8;
  const int sr1 = sr0 + 32;

  // prefetch stage k0=0
  f16x8 rA0h = *(const f16x8*)(xh + (size_t)(m0 + sr0) * EE + sc0);
  f16x8 rA0l = *(const f16x8*)(xl + (size_t)(m0 + sr0) * EE + sc0);
  f16x8 rB0h = *(const f16x8*)(Bh + (size_t)(n0 + sr0) * EE + sc0);
  f16x8 rB0l = *(const f16x8*)(Bl + (size_t)(n0 + sr0) * EE + sc0);
  f16x8 rA1h = *(const f16x8*)(xh + (size_t)(m0 + sr1) * EE + sc0);
  f16x8 rA1l = *(const f16x8*)(xl + (size_t)(m0 + sr1) * EE + sc0);
  f16x8 rB1h = *(const f16x8*)(Bh + (size_t)(n0 + sr1) * EE + sc0);
  f16x8 rB1l = *(const f16x8*)(Bl + (size_t)(n0 + sr1) * EE + sc0);

  f32x4 acc[4] = {};
  for (int k0 = 0; k0 < EE; k0 += 64) {
    if (k0) __syncthreads();
    *(f16x8*)&LAh[sr0][sc0] = rA0h;
    *(f16x8*)&LAl[sr0][sc0] = rA0l;
    *(f16x8*)&LBh[sr0][sc0] = rB0h;
    *(f16x8*)&LBl[sr0][sc0] = rB0l;
    *(f16x8*)&LAh[sr1][sc0] = rA1h;
    *(f16x8*)&LAl[sr1][sc0] = rA1l;
    *(f16x8*)&LBh[sr1][sc0] = rB1h;
    *(f16x8*)&LBl[sr1][sc0] = rB1l;
    __syncthreads();
    if (k0 + 64 < EE) {
      const int kn = k0 + 64;
      rA0h = *(const f16x8*)(xh + (size_t)(m0 + sr0) * EE + kn + sc0);
      rA0l = *(const f16x8*)(xl + (size_t)(m0 + sr0) * EE + kn + sc0);
      rB0h = *(const f16x8*)(Bh + (size_t)(n0 + sr0) * EE + kn + sc0);
      rB0l = *(const f16x8*)(Bl + (size_t)(n0 + sr0) * EE + kn + sc0);
      rA1h = *(const f16x8*)(xh + (size_t)(m0 + sr1) * EE + kn + sc0);
      rA1l = *(const f16x8*)(xl + (size_t)(m0 + sr1) * EE + kn + sc0);
      rB1h = *(const f16x8*)(Bh + (size_t)(n0 + sr1) * EE + kn + sc0);
      rB1l = *(const f16x8*)(Bl + (size_t)(n0 + sr1) * EE + kn + sc0);
    }
#pragma unroll
    for (int kk = 0; kk < 64; kk += 32) {
      f16x8 ah = *(const f16x8*)&LAh[wave * 16 + l16][kk + quad * 8];
      f16x8 al = *(const f16x8*)&LAl[wave * 16 + l16][kk + quad * 8];
#pragma unroll
      for (int nt = 0; nt < 4; ++nt) {
        f16x8 bhf = *(const f16x8*)&LBh[nt * 16 + l16][kk + quad * 8];
        f16x8 blf = *(const f16x8*)&LBl[nt * 16 + l16][kk + quad * 8];
        acc[nt] = __builtin_amdgcn_mfma_f32_16x16x32_f16(ah, bhf, acc[nt], 0, 0, 0);
        acc[nt] = __builtin_amdgcn_mfma_f32_16x16x32_f16(ah, blf, acc[nt], 0, 0, 0);
        acc[nt] = __builtin_amdgcn_mfma_f32_16x16x32_f16(al, bhf, acc[nt], 0, 0, 0);
      }
    }
  }
  const float* bias = (which == 0) ? bq : (which == 1) ? bk : bv;
  if (which == 2) {
    // V path: bias-add, transpose via LDS, store split-f16 [bh][d][si]
    __syncthreads();  // main-loop LDS reads done before overwrite
#pragma unroll
    for (int nt = 0; nt < 4; ++nt) {
      const int dcol = nt * 16 + l16;             // d within head
      const float bb = bias[n0 + nt * 16 + l16];  // n0 = head*64
#pragma unroll
      for (int r = 0; r < 4; ++r)
        TR[dcol][wave * 16 + quad * 4 + r] = acc[nt][r] + bb;
    }
    __syncthreads();
    const int d = tid >> 2, cc = (tid & 3) * 16;
    const int bh = (m0 >> 9) * NH + (n0 >> 6);
    const int si0 = m0 & 511;
    f16x8 h0, l0, h1, l1;
#pragma unroll
    for (int jj = 0; jj < 8; ++jj) {
      HL r0 = split16(TR[d][cc + jj]);
      HL r1 = split16(TR[d][cc + 8 + jj]);
      h0[jj] = r0.h; l0[jj] = r0.l;
      h1[jj] = r1.h; l1[jj] = r1.l;
    }
    _Float16* dh = vth + ((size_t)bh * HD + d) * SS + si0 + cc;
    _Float16* dl = vtl + ((size_t)bh * HD + d) * SS + si0 + cc;
    *(f16x8*)dh = h0;
    *(f16x8*)(dh + 8) = h1;
    *(f16x8*)dl = l0;
    *(f16x8*)(dl + 8) = l1;
  } else {
    const float postscale = (which == 0) ? 0.125f : 1.0f;
    const int mbase = m0 + wave * 16 + quad * 4;
#pragma unroll
    for (int nt = 0; nt < 4; ++nt) {
      const int col = n0 + nt * 16 + l16;
      const float bb = bias[col];
      const int hh = col >> 6, d = col & 63;
#pragma unroll
      for (int r = 0; r < 4; ++r) {
        const int mm = mbase + r;
        const int b_ = mm >> 9, si = mm & 511;
        const size_t idx = (((size_t)(b_ * NH + hh)) * SS + si) * HD + d;
        const float val = (acc[nt][r] + bb) * postscale;
        HL sp = split16(val);
        (which ? kh : qh)[idx] = sp.h;
        (which ? kl : ql)[idx] = sp.l;
      }
    }
  }
}

// ---------------------------------------------------------------------------
// K_scores: s = clip(q.k^T, -15, 15) via 3-term f16 MFMA (q pre-scaled).
// LDS-staged: Q and K 64-row tiles staged once per block, then pure
// ds_read+MFMA. grid (8 jT, 8 iT, 32 bh), block 256 (4 waves stacked in m).
__global__ __launch_bounds__(256) void k_scores_mfma(
    const _Float16* __restrict__ qh, const _Float16* __restrict__ ql,
    const _Float16* __restrict__ kh, const _Float16* __restrict__ kl,
    float* __restrict__ s) {
  const int bh = blockIdx.z;
  const int i0 = blockIdx.y * 64, j0 = blockIdx.x * 64;
  const int tid = threadIdx.x;
  const int wave = tid >> 6, lane = tid & 63;
  const int quad = lane >> 4, l16 = lane & 15;

  __shared__ _Float16 Qh[64][72], Ql[64][72], Kh[64][72], Kl[64][72];
  // stage: thread t -> row r = t>>2, cols c..c+15 (two f16x8 per array)
  const int r = tid >> 2, c = (tid & 3) * 16;
  {
    const size_t qoff = ((size_t)bh * SS + i0 + r) * HD + c;
    const size_t koff = ((size_t)bh * SS + j0 + r) * HD + c;
    *(f16x8*)&Qh[r][c] = *(const f16x8*)(qh + qoff);
    *(f16x8*)&Qh[r][c + 8] = *(const f16x8*)(qh + qoff + 8);
    *(f16x8*)&Ql[r][c] = *(const f16x8*)(ql + qoff);
    *(f16x8*)&Ql[r][c + 8] = *(const f16x8*)(ql + qoff + 8);
    *(f16x8*)&Kh[r][c] = *(const f16x8*)(kh + koff);
    *(f16x8*)&Kh[r][c + 8] = *(const f16x8*)(kh + koff + 8);
    *(f16x8*)&Kl[r][c] = *(const f16x8*)(kl + koff);
    *(f16x8*)&Kl[r][c + 8] = *(const f16x8*)(kl + koff + 8);
  }
  __syncthreads();

  f16x8 a_hi[2], a_lo[2];
#pragma unroll
  for (int ks = 0; ks < 2; ++ks) {
    a_hi[ks] = *(const f16x8*)&Qh[wave * 16 + l16][ks * 32 + quad * 8];
    a_lo[ks] = *(const f16x8*)&Ql[wave * 16 + l16][ks * 32 + quad * 8];
  }
  f32x4 acc[4] = {};
#pragma unroll
  for (int ks = 0; ks < 2; ++ks) {
#pragma unroll
    for (int t = 0; t < 4; ++t) {
      f16x8 b_hi = *(const f16x8*)&Kh[t * 16 + l16][ks * 32 + quad * 8];
      f16x8 b_lo = *(const f16x8*)&Kl[t * 16 + l16][ks * 32 + quad * 8];
      acc[t] = __builtin_amdgcn_mfma_f32_16x16x32_f16(a_hi[ks], b_hi,
                                                      acc[t], 0, 0, 0);
      acc[t] = __builtin_amdgcn_mfma_f32_16x16x32_f16(a_hi[ks], b_lo,
                                                      acc[t], 0, 0, 0);
      acc[t] = __builtin_amdgcn_mfma_f32_16x16x32_f16(a_lo[ks], b_hi,
                                                      acc[t], 0, 0, 0);
    }
  }
  float* sb = s + (size_t)bh * SS * SS;
#pragma unroll
  for (int t = 0; t < 4; ++t) {
#pragma unroll
    for (int r2 = 0; r2 < 4; ++r2) {
      float val = clampf(acc[t][r2], -15.0f, 15.0f);  // inputs finite
      sb[(size_t)(i0 + wave * 16 + quad * 4 + r2) * SS + j0 + t * 16 + l16] = val;
    }
  }
}

// ---------------------------------------------------------------------------
// K_rowstat: per-row fused ma + autopoietic transform (one wave per row).
__global__ __launch_bounds__(64) void k_rowstat(
    const float* __restrict__ s, const float* __restrict__ T,
    float* __restrict__ ma, float* __restrict__ t_un,
    float* __restrict__ rowred) {
  const int row = blockIdx.x;  // b*S + i
  const int b_ = row >> 9, i = row & 511;
  const int lane = threadIdx.x;

  float4 a0 = {0.f, 0.f, 0.f, 0.f}, a1 = {0.f, 0.f, 0.f, 0.f};
#pragma unroll
  for (int hh = 0; hh < NH; ++hh) {
    const float4* p = reinterpret_cast<const float4*>(
                          s + (((size_t)(b_ * NH + hh) * SS) + i) * SS) +
                      lane * 2;
    float4 u0 = p[0], u1 = p[1];
    a0.x += u0.x; a0.y += u0.y; a0.z += u0.z; a0.w += u0.w;
    a1.x += u1.x; a1.y += u1.y; a1.z += u1.z; a1.w += u1.w;
  }
  float m[8] = {a0.x * 0.125f, a0.y * 0.125f, a0.z * 0.125f, a0.w * 0.125f,
                a1.x * 0.125f, a1.y * 0.125f, a1.z * 0.125f, a1.w * 0.125f};
  {
    float4* mp = reinterpret_cast<float4*>(ma + ((size_t)b_ * SS + i) * SS) +
                 lane * 2;
    float4 w0 = {m[0], m[1], m[2], m[3]}, w1v = {m[4], m[5], m[6], m[7]};
    mp[0] = w0;
    mp[1] = w1v;
  }
  float sma = 0.f, sma2 = 0.f, mabs = 0.f;
#pragma unroll
  for (int e = 0; e < 8; ++e) {
    sma += m[e];
    sma2 += m[e] * m[e];
    mabs = fmaxf(mabs, fabsf(m[e]));
  }
  sma = waveRedSum(sma);
  sma2 = waveRedSum(sma2);
  mabs = waveRedMax(mabs);

  float ex[8], esum = 0.f;
#pragma unroll
  for (int e = 0; e < 8; ++e) {
    ex[e] = expf(clampf(m[e], -10.f, 10.f));
    esum += ex[e];
  }
  esum = waveRedSum(esum);
  float inv = 1.0f / esum;
  float Hv[8], sH = 0.f;
#pragma unroll
  for (int e = 0; e < 8; ++e) {
    float p = ex[e] * inv;
    Hv[e] = -p * logf(p + 1e-6f);
    sH += Hv[e];
  }
  sH = waveRedSum(sH);

  float fx[8], fsum = 0.f;
#pragma unroll
  for (int e = 0; e < 8; ++e) {
    fx[e] = expf(3.0f * Hv[e]);
    fsum += fx[e];
  }
  fsum = waveRedSum(fsum);
  float finv = 1.0f / fsum;

  float t[8], st = 0.f, st2 = 0.f;
#pragma unroll
  for (int e = 0; e < 8; ++e) {
    float sa = clampf(m[e], -8.f, 8.f) * 0.05f;
    float pos = (sa + 0.4f) * ((float)NTAB / 0.8f);
    int idx = (int)pos;
    idx = idx < 0 ? 0 : (idx > NTAB - 1 ? NTAB - 1 : idx);
    float frac = pos - (float)idx;
    float g0 = T[idx], g1 = T[idx + 1];
    float sig = g0 + (g1 - g0) * frac;
    t[e] = sig * fx[e] * finv;
    st += t[e];
    st2 += t[e] * t[e];
  }
  st = waveRedSum(st);
  st2 = waveRedSum(st2);
  {
    float4* tp = reinterpret_cast<float4*>(t_un + ((size_t)b_ * SS + i) * SS) +
                 lane * 2;
    float4 w0 = {t[0], t[1], t[2], t[3]}, w1v = {t[4], t[5], t[6], t[7]};
    tp[0] = w0;
    tp[1] = w1v;
  }
  if (lane == 0) {
    float* rp = rowred + (size_t)row * 8;
    rp[0] = sma; rp[1] = sma2; rp[2] = mabs;
    rp[3] = st;  rp[4] = st2;  rp[5] = sH;
  }
}

// ---------------------------------------------------------------------------
// K_consts: reduce per-row partials -> per-batch blend constants.
__global__ __launch_bounds__(256) void k_consts(
    const float* __restrict__ rowred, float* __restrict__ cst) {
  const int b_ = blockIdx.x;
  const int tid = threadIdx.x;
  __shared__ float red[4];
  const float* r0 = rowred + ((size_t)b_ * SS + tid * 2) * 8;
  const float* r1 = r0 + 8;
  float sma = blockRedSum(r0[0] + r1[0], red);
  float sma2 = blockRedSum(r0[1] + r1[1], red);
  float mabs = blockRedMax(fmaxf(r0[2], r1[2]), red);
  float st = blockRedSum(r0[3] + r1[3], red);
  float st2 = blockRedSum(r0[4] + r1[4], red);
  float sH = blockRedSum(r0[5] + r1[5], red);
  if (tid == 0) {
    const float N = (float)(SS * SS);
    float eo = sqrtf(sma2) + 1e-4f;
    float et = sqrtf(st2) + 1e-4f;
    float r = clampf(eo / et, 0.8f, 1.2f);
    float tmean = r * st / N;
    float om = sma / N;
    float vart = r * r * fmaxf(st2 / N - (st / N) * (st / N), 0.f);
    float tstd = sqrtf(fmaxf(vart, 0.01f));
    float varo = fmaxf(sma2 / N - om * om, 0.f);
    float ostd = sqrtf(fmaxf(varo, 0.01f));
    float gd = clampf(ostd / tstd, 0.8f, 1.2f);
    float ar = clampf(mabs, 1.f, 10.f);
    float sm = clampf(0.3f / log1pf(ar), 0.1f, 0.5f);
    float ent = sH / N;
    float ne = ent / logf((float)SS);
    float rr = 0.4f * (1.f - clampf(ne, 0.f, 0.4f));
    float G = sm * gd;
    cst[b_ * 4 + 0] = rr * (1.f - G) * tmean;  // c0
    cst[b_ * 4 + 1] = rr * G * r;              // c1 (multiplies t_un)
    cst[b_ * 4 + 2] = rr;                      // c2 (multiplies ma)
  }
}

// ---------------------------------------------------------------------------
// K_av_fused: out = softmax(blend(s)) @ v with NO materialized p.
// out = (sum_j e_ij v_j)/Z_i. Stage threads (tid<128) compute unnormalized
// e' = exp(blend)*2^-16 (f16-safe), split into LDS, accumulate Z partials.
// m-tile = 32 rows -> grid (16 mb, 32 bh) = 512 blocks = 2/CU for inter-block
// overlap. Waves run pure ds_read+MFMA; epilogue divides by Z.
__global__ __launch_bounds__(256) void k_av_fused(
    const float* __restrict__ s, const float* __restrict__ ma,
    const float* __restrict__ t_un, const float* __restrict__ cst,
    const float* __restrict__ tau, const _Float16* __restrict__ vth,
    const _Float16* __restrict__ vtl, _Float16* __restrict__ oh,
    _Float16* __restrict__ ol) {
  const int bh = blockIdx.y;
  const int b_ = bh >> 3, hh = bh & 7;
  const int m0 = blockIdx.x * 32;
  const int tid = threadIdx.x;
  const int wave = tid >> 6, lane = tid & 63;
  const int quad = lane >> 4, l16 = lane & 15;

  const float c0 = cst[b_ * 4 + 0], c1 = cst[b_ * 4 + 1], c2 = cst[b_ * 4 + 2];
  const float itau = 1.0f / tau[0];

  __shared__ _Float16 Ph[32][40], Pl[32][40];
  __shared__ float Zp[32][4];

  const bool stager = (tid < 128);
  const int srow = tid >> 2;          // 0..31 valid when stager
  const int ci = tid & 3;
  const int schunk = ci * 8;
  const size_t sbase = ((size_t)bh * SS + m0 + (srow & 31)) * SS + schunk;
  const size_t mbase = ((size_t)b_ * SS + m0 + (srow & 31)) * SS + schunk;

  float4 sv0, sv1, mv0, mv1, tv0, tv1;
  if (stager) {
    sv0 = *(const float4*)(s + sbase);
    sv1 = *(const float4*)(s + sbase + 4);
    mv0 = *(const float4*)(ma + mbase);
    mv1 = *(const float4*)(ma + mbase + 4);
    tv0 = *(const float4*)(t_un + mbase);
    tv1 = *(const float4*)(t_un + mbase + 4);
  }

  float zpart = 0.f;
  f32x4 acc[2] = {};
  for (int k0 = 0; k0 < SS; k0 += 32) {
    if (k0) __syncthreads();  // prior-stage LDS reads done
    if (stager) {
      float svv[8] = {sv0.x, sv0.y, sv0.z, sv0.w, sv1.x, sv1.y, sv1.z, sv1.w};
      float mvv[8] = {mv0.x, mv0.y, mv0.z, mv0.w, mv1.x, mv1.y, mv1.z, mv1.w};
      float tvv[8] = {tv0.x, tv0.y, tv0.z, tv0.w, tv1.x, tv1.y, tv1.z, tv1.w};
      f16x8 hv, lv;
#pragma unroll
      for (int j = 0; j < 8; ++j) {
        float vv = (svv[j] + c0 + c1 * tvv[j] - c2 * mvv[j]) * itau;
        float e = expf(vv) * 1.52587890625e-05f;  // * 2^-16
        zpart += e;
        HL r = split16(e);
        hv[j] = r.h;
        lv[j] = r.l;
      }
      *(f16x8*)&Ph[srow][schunk] = hv;
      *(f16x8*)&Pl[srow][schunk] = lv;
    }
    __syncthreads();
    if (stager && k0 + 32 < SS) {
      sv0 = *(const float4*)(s + sbase + k0 + 32);
      sv1 = *(const float4*)(s + sbase + k0 + 36);
      mv0 = *(const float4*)(ma + mbase + k0 + 32);
      mv1 = *(const float4*)(ma + mbase + k0 + 36);
      tv0 = *(const float4*)(t_un + mbase + k0 + 32);
      tv1 = *(const float4*)(t_un + mbase + k0 + 36);
    }
    const size_t boff = ((size_t)bh * HD + wave * 16 + l16) * SS + k0 + quad * 8;
    f16x8 bh_ = *(const f16x8*)(vth + boff);
    f16x8 bl_ = *(const f16x8*)(vtl + boff);
#pragma unroll
    for (int mt = 0; mt < 2; ++mt) {
      f16x8 ah = *(const f16x8*)&Ph[mt * 16 + l16][quad * 8];
      f16x8 al = *(const f16x8*)&Pl[mt * 16 + l16][quad * 8];
      acc[mt] = __builtin_amdgcn_mfma_f32_16x16x32_f16(ah, bh_, acc[mt], 0, 0, 0);
      acc[mt] = __builtin_amdgcn_mfma_f32_16x16x32_f16(ah, bl_, acc[mt], 0, 0, 0);
      acc[mt] = __builtin_amdgcn_mfma_f32_16x16x32_f16(al, bh_, acc[mt], 0, 0, 0);
    }
  }
  __syncthreads();
  if (stager) Zp[srow][ci] = zpart;
  __syncthreads();
#pragma unroll
  for (int mt = 0; mt < 2; ++mt) {
#pragma unroll
    for (int r = 0; r < 4; ++r) {
      const int lr = mt * 16 + quad * 4 + r;  // local row 0..31
      const float Z = Zp[lr][0] + Zp[lr][1] + Zp[lr][2] + Zp[lr][3];
      const float oV = acc[mt][r] / Z;
      const int si = m0 + lr;
      const size_t idx =
          ((size_t)(b_ * SS + si)) * EE + hh * HD + wave * 16 + l16;
      HL sp = split16(oV);
      oh[idx] = sp.h;
      ol[idx] = sp.l;
    }
  }
}

// ---------------------------------------------------------------------------
// K_out: LDS-staged 3-term f16 MFMA GEMM with register-prefetch pipelining,
// fp32 output + bias. grid (8 nb, 32 mb), block 256.
__global__ __launch_bounds__(256) void k_out_mfma(
    const _Float16* __restrict__ oh, const _Float16* __restrict__ ol,
    const _Float16* __restrict__ Wth, const _Float16* __restrict__ Wtl,
    const float* __restrict__ bo, float* __restrict__ out) {
  const int tid = threadIdx.x;
  const int wave = tid >> 6, lane = tid & 63;
  const int quad = lane >> 4, l16 = lane & 15;
  const int m0 = blockIdx.y * 64;
  const int n0 = blockIdx.x * 64;
  const _Float16* Bh = Wth + (size_t)3 * EE * EE;  // Wo^T
  const _Float16* Bl = Wtl + (size_t)3 * EE * EE;

  __shared__ _Float16 LAh[64][72], LAl[64][72], LBh[64][72], LBl[64][72];

  const int sr0 = tid >> 3, sc0 = (tid & 7) * 8;
  const int sr1 = sr0 + 32;

  f16x8 rA0h = *(const f16x8*)(oh + (size_t)(m0 + sr0) * EE + sc0);
  f16x8 rA0l = *(const f16x8*)(ol + (size_t)(m0 + sr0) * EE + sc0);
  f16x8 rB0h = *(const f16x8*)(Bh + (size_t)(n0 + sr0) * EE + sc0);
  f16x8 rB0l = *(const f16x8*)(Bl + (size_t)(n0 + sr0) * EE + sc0);
  f16x8 rA1h = *(const f16x8*)(oh + (size_t)(m0 + sr1) * EE + sc0);
  f16x8 rA1l = *(const f16x8*)(ol + (size_t)(m0 + sr1) * EE + sc0);
  f16x8 rB1h = *(const f16x8*)(Bh + (size_t)(n0 + sr1) * EE + sc0);
  f16x8 rB1l = *(const f16x8*)(Bl + (size_t)(n0 + sr1) * EE + sc0);

  f32x4 acc[4] = {};
  for (int k0 = 0; k0 < EE; k0 += 64) {
    if (k0) __syncthreads();
    *(f16x8*)&LAh[sr0][sc0] = rA0h;
    *(f16x8*)&LAl[sr0][sc0] = rA0l;
    *(f16x8*)&LBh[sr0][sc0] = rB0h;
    *(f16x8*)&LBl[sr0][sc0] = rB0l;
    *(f16x8*)&LAh[sr1][sc0] = rA1h;
    *(f16x8*)&LAl[sr1][sc0] = rA1l;
    *(f16x8*)&LBh[sr1][sc0] = rB1h;
    *(f16x8*)&LBl[sr1][sc0] = rB1l;
    __syncthreads();
    if (k0 + 64 < EE) {
      const int kn = k0 + 64;
      rA0h = *(const f16x8*)(oh + (size_t)(m0 + sr0) * EE + kn + sc0);
      rA0l = *(const f16x8*)(ol + (size_t)(m0 + sr0) * EE + kn + sc0);
      rB0h = *(const f16x8*)(Bh + (size_t)(n0 + sr0) * EE + kn + sc0);
      rB0l = *(const f16x8*)(Bl + (size_t)(n0 + sr0) * EE + kn + sc0);
      rA1h = *(const f16x8*)(oh + (size_t)(m0 + sr1) * EE + kn + sc0);
      rA1l = *(const f16x8*)(ol + (size_t)(m0 + sr1) * EE + kn + sc0);
      rB1h = *(const f16x8*)(Bh + (size_t)(n0 + sr1) * EE + kn + sc0);
      rB1l = *(const f16x8*)(Bl + (size_t)(n0 + sr1) * EE + kn + sc0);
    }
#pragma unroll
    for (int kk = 0; kk < 64; kk += 32) {
      f16x8 ah = *(const f16x8*)&LAh[wave * 16 + l16][kk + quad * 8];
      f16x8 al = *(const f16x8*)&LAl[wave * 16 + l16][kk + quad * 8];
#pragma unroll
      for (int nt = 0; nt < 4; ++nt) {
        f16x8 bhf = *(const f16x8*)&LBh[nt * 16 + l16][kk + quad * 8];
        f16x8 blf = *(const f16x8*)&LBl[nt * 16 + l16][kk + quad * 8];
        acc[nt] = __builtin_amdgcn_mfma_f32_16x16x32_f16(ah, bhf, acc[nt], 0, 0, 0);
        acc[nt] = __builtin_amdgcn_mfma_f32_16x16x32_f16(ah, blf, acc[nt], 0, 0, 0);
        acc[nt] = __builtin_amdgcn_mfma_f32_16x16x32_f16(al, bhf, acc[nt], 0, 0, 0);
      }
    }
  }
  const int mbase = m0 + wave * 16 + quad * 4;
#pragma unroll
  for (int nt = 0; nt < 4; ++nt) {
    const int col = n0 + nt * 16 + l16;
    const float bb = bo[col];
#pragma unroll
    for (int r = 0; r < 4; ++r) {
      const int m = mbase + r;
      out[(size_t)m * EE + col] = acc[nt][r] + bb;
    }
  }
}

// ---------------------------------------------------------------------------
extern "C" void kernel_launch(void* const* d_in, const int* in_sizes, int n_in,
                              void* d_out, int out_size, void* d_ws,
                              size_t ws_size, hipStream_t stream) {
  const float* x = (const float*)d_in[0];
  const float* Wq = (const float*)d_in[1];
  const float* bq = (const float*)d_in[2];
  const float* Wk = (const float*)d_in[3];
  const float* bk = (const float*)d_in[4];
  const float* Wv = (const float*)d_in[5];
  const float* bv = (const float*)d_in[6];
  const float* Wo = (const float*)d_in[7];
  const float* bo = (const float*)d_in[8];
  const float* w1 = (const float*)d_in[9];
  const float* b1 = (const float*)d_in[10];
  const float* w2 = (const float*)d_in[11];
  const float* b2 = (const float*)d_in[12];
  const float* tau = (const float*)d_in[13];
  float* out = (float*)d_out;

  const size_t NX = (size_t)2048 * EE;           // 1M elems (x, o)
  const size_t NW = (size_t)4 * EE * EE;         // 1M elems (4 W's)
  const size_t NQK = (size_t)BB * NH * SS * HD;  // 1M elems
  const size_t NS = (size_t)BB * NH * SS * SS;   // 8.39M elems

  _Float16* xh = (_Float16*)d_ws;
  _Float16* xl = xh + NX;
  _Float16* Wth = xl + NX;
  _Float16* Wtl = Wth + NW;
  _Float16* qh = Wtl + NW;
  _Float16* ql = qh + NQK;
  _Float16* kh = ql + NQK;
  _Float16* kl = kh + NQK;
  _Float16* vth = kl + NQK;
  _Float16* vtl = vth + NQK;
  float* s = (float*)(vtl + NQK);
  float* ma = s + NS;
  float* t_un = ma + (size_t)BB * SS * SS;
  float* T = t_un + (size_t)BB * SS * SS;
  float* rowred = T + 8192;
  float* cst = rowred + 2048 * 8;
  _Float16* oh = xh;  // alias: x dead after k_qkv_mfma
  _Float16* ol = xl;

  k_prep<<<785, 256, 0, stream>>>(w1, b1, w2, b2, T, x, xh, xl, Wq, Wk, Wv, Wo,
                                  Wth, Wtl);
  k_qkv_mfma<<<dim3(8, 32, 3), 256, 0, stream>>>(xh, xl, Wth, Wtl, bq, bk, bv,
                                                 qh, ql, kh, kl, vth, vtl);
  k_scores_mfma<<<dim3(8, 8, 32), 256, 0, stream>>>(qh, ql, kh, kl, s);
  k_rowstat<<<2048, 64, 0, stream>>>(s, T, ma, t_un, rowred);
  k_consts<<<4, 256, 0, stream>>>(rowred, cst);
  k_av_fused<<<dim3(16, 32), 256, 0, stream>>>(s, ma, t_un, cst, tau, vth, vtl,
                                               oh, ol);
  k_out_mfma<<<dim3(8, 32), 256, 0, stream>>>(oh, ol, Wth, Wtl, bo, out);
}